// Round 7
// baseline (250.617 us; speedup 1.0000x reference)
//
#include <hip/hip_runtime.h>

typedef unsigned short u16;
typedef unsigned int u32;
typedef __bf16 bf16x8 __attribute__((ext_vector_type(8)));
typedef float f32x4 __attribute__((ext_vector_type(4)));
typedef float f32x16 __attribute__((ext_vector_type(16)));
typedef u16 u16x8 __attribute__((ext_vector_type(8)));
typedef u16 u16x4 __attribute__((ext_vector_type(4)));
typedef u32 u32x4 __attribute__((ext_vector_type(4)));

#define LN_EPS 1e-5f
#define SIG_SCALE_F 0.35355339059327379f /* 64^-0.25 */
#define NLOG2E -1.4426950408889634f
#define BIAS_L2E 4.328085122666891f /* 3*log2(e) */

__device__ __forceinline__ u16 f2bf(float f) {
    u32 u = __builtin_bit_cast(u32, f);
    u32 r = u + 0x7fffu + ((u >> 16) & 1u);
    return (u16)(r >> 16);
}
__device__ __forceinline__ float bf2f(u16 v) {
    return __builtin_bit_cast(float, (u32)v << 16);
}
// pack high-16s of two f32 (truncating bf16 cvt, 1 v_perm): low16=a, high16=b
__device__ __forceinline__ u32 pk_hi(float a, float b) {
    return __builtin_amdgcn_perm(__builtin_bit_cast(u32, b), __builtin_bit_cast(u32, a),
                                 0x07060302u);
}

// async global->LDS, 16B per lane; lds base wave-uniform (HW adds lane*16)
__device__ __forceinline__ void gload16(const u16* g, u16* lds) {
    __builtin_amdgcn_global_load_lds(
        (const __attribute__((address_space(1))) u32*)g,
        (__attribute__((address_space(3))) u32*)lds, 16, 0, 0);
}

// ---------------------------------------------------------------------------
// GEMM core: acc[4][4] += A[M,K] @ B[N,K]^T 128x128 tile, BK=32,
// global_load_lds staging, XOR-swizzled LDS (64B rows, chunk c^=row&3).
// ---------------------------------------------------------------------------
__device__ __forceinline__ void gemm_core(f32x4 acc[4][4],
                                          const u16* __restrict__ A, const u16* __restrict__ B,
                                          int Kiter, int lda, int ldb,
                                          long m0, long n0, u16* As, u16* Bs) {
    const int tid = threadIdx.x;
    const int lane = tid & 63;
    const int wave = tid >> 6;
    const int r15 = lane & 15;
    const int qd = lane >> 4;
    const int wm = (wave >> 1) * 64;
    const int wn = (wave & 1) * 64;

    const int srow = wave * 16 + (lane >> 2);
    const int c0 = (lane & 3) ^ (srow & 3);
    const u16* Ap0 = A + (m0 + srow) * lda + c0 * 8;
    const u16* Ap1 = A + (m0 + srow + 64) * lda + c0 * 8;
    const u16* Bp0 = B + (n0 + srow) * ldb + c0 * 8;
    const u16* Bp1 = B + (n0 + srow + 64) * ldb + c0 * 8;
    u16* As0 = As + wave * 512;
    u16* As1 = As + (wave + 4) * 512;
    u16* Bs0 = Bs + wave * 512;
    u16* Bs1 = Bs + (wave + 4) * 512;

    for (int kt = 0; kt < Kiter; kt += 32) {
        __syncthreads();
        gload16(Ap0 + kt, As0);
        gload16(Ap1 + kt, As1);
        gload16(Bp0 + kt, Bs0);
        gload16(Bp1 + kt, Bs1);
        __syncthreads();
        bf16x8 af[4], bfr[4];
#pragma unroll
        for (int i = 0; i < 4; i++) {
            int row = wm + i * 16 + r15;
            af[i] = *(const bf16x8*)(As + row * 32 + ((qd ^ (row & 3)) * 8));
        }
#pragma unroll
        for (int j = 0; j < 4; j++) {
            int row = wn + j * 16 + r15;
            bfr[j] = *(const bf16x8*)(Bs + row * 32 + ((qd ^ (row & 3)) * 8));
        }
#pragma unroll
        for (int i = 0; i < 4; i++)
#pragma unroll
            for (int j = 0; j < 4; j++)
                acc[i][j] = __builtin_amdgcn_mfma_f32_16x16x32_bf16(af[i], bfr[j], acc[i][j], 0, 0, 0);
    }
}

// ---------------------------------------------------------------------------
// Fused q/k/v projections with per-head LayerNorm epilogue for q,k.
// grid (32, 8, 3). Wave's 64-col span == one head; stats via shfl over r15.
// ---------------------------------------------------------------------------
__global__ __launch_bounds__(256) void gemm_qkv(const u16* __restrict__ xq, const u16* __restrict__ keyb,
                                                const u16* __restrict__ Wqb, const u16* __restrict__ Wkb,
                                                const u16* __restrict__ Wvb,
                                                const float* __restrict__ qns, const float* __restrict__ qnb,
                                                const float* __restrict__ kns, const float* __restrict__ knb,
                                                u16* __restrict__ qln, u16* __restrict__ kln,
                                                u16* __restrict__ vb) {
    __shared__ __attribute__((aligned(16))) u16 As[128 * 32];
    __shared__ __attribute__((aligned(16))) u16 Bs[128 * 32];
    const int z = blockIdx.z;
    const u16* A = (z == 0) ? xq : keyb;
    const u16* B = (z == 0) ? Wqb : ((z == 1) ? Wkb : Wvb);
    u16* C = (z == 0) ? qln : ((z == 1) ? kln : vb);
    const long m0 = (long)blockIdx.x * 128;
    const long n0 = (long)blockIdx.y * 128;

    f32x4 acc[4][4];
#pragma unroll
    for (int i = 0; i < 4; i++)
#pragma unroll
        for (int j = 0; j < 4; j++) acc[i][j] = (f32x4){0.f, 0.f, 0.f, 0.f};

    gemm_core(acc, A, B, 1024, 1024, 1024, m0, n0, As, Bs);

    const int lane = threadIdx.x & 63;
    const int wave = threadIdx.x >> 6;
    const int r15 = lane & 15;
    const int qd = lane >> 4;
    const int wm = (wave >> 1) * 64;
    const int wn = (wave & 1) * 64;

    if (z <= 1) {
        const float* sc_ = (z == 0) ? qns : kns;
        const float* bs_ = (z == 0) ? qnb : knb;
        float scl[4], bia[4];
#pragma unroll
        for (int j = 0; j < 4; j++) {
            scl[j] = sc_[j * 16 + r15] * SIG_SCALE_F;
            bia[j] = bs_[j * 16 + r15] * SIG_SCALE_F;
        }
#pragma unroll
        for (int i = 0; i < 4; i++) {
#pragma unroll
            for (int rr = 0; rr < 4; rr++) {
                float a0 = acc[i][0][rr], a1 = acc[i][1][rr], a2 = acc[i][2][rr], a3 = acc[i][3][rr];
                float s1 = (a0 + a1) + (a2 + a3);
                float s2 = __builtin_fmaf(a3, a3,
                           __builtin_fmaf(a2, a2, __builtin_fmaf(a1, a1, a0 * a0)));
#pragma unroll
                for (int off = 1; off <= 8; off <<= 1) {
                    s1 += __shfl_xor(s1, off, 64);
                    s2 += __shfl_xor(s2, off, 64);
                }
                float mu = s1 * (1.0f / 64.0f);
                float var = __builtin_fmaf(-mu, mu, s2 * (1.0f / 64.0f));
                float rs = rsqrtf(var + LN_EPS);
                long row = m0 + wm + i * 16 + qd * 4 + rr;
#pragma unroll
                for (int j = 0; j < 4; j++) {
                    long col = n0 + wn + j * 16 + r15;
                    float o = __builtin_fmaf((acc[i][j][rr] - mu) * rs, scl[j], bia[j]);
                    C[row * 1024 + col] = f2bf(o);
                }
            }
        }
    } else {
#pragma unroll
        for (int i = 0; i < 4; i++)
#pragma unroll
            for (int rr = 0; rr < 4; rr++) {
                long row = m0 + wm + i * 16 + qd * 4 + rr;
#pragma unroll
                for (int j = 0; j < 4; j++)
                    C[row * 1024 + n0 + wn + j * 16 + r15] = f2bf(acc[i][j][rr]);
            }
    }
}

// output projection, split-K=2: grid (32, 8, 2), bf16 partials
__global__ __launch_bounds__(256) void gemm_o(const u16* __restrict__ ctx, const u16* __restrict__ Wob,
                                              u16* __restrict__ opre0, u16* __restrict__ opre1) {
    __shared__ __attribute__((aligned(16))) u16 As[128 * 32];
    __shared__ __attribute__((aligned(16))) u16 Bs[128 * 32];
    const int z = blockIdx.z;
    const int koff = z * 512;
    u16* C = z ? opre1 : opre0;
    const long m0 = (long)blockIdx.x * 128;
    const long n0 = (long)blockIdx.y * 128;
    f32x4 acc[4][4];
#pragma unroll
    for (int i = 0; i < 4; i++)
#pragma unroll
        for (int j = 0; j < 4; j++) acc[i][j] = (f32x4){0.f, 0.f, 0.f, 0.f};
    gemm_core(acc, ctx + koff, Wob + koff, 512, 1024, 1024, m0, n0, As, Bs);

    const int lane = threadIdx.x & 63;
    const int wave = threadIdx.x >> 6;
    const int r15 = lane & 15;
    const int qd = lane >> 4;
    const int wm = (wave >> 1) * 64;
    const int wn = (wave & 1) * 64;
#pragma unroll
    for (int i = 0; i < 4; i++)
#pragma unroll
        for (int rr = 0; rr < 4; rr++) {
            long row = m0 + wm + i * 16 + qd * 4 + rr;
#pragma unroll
            for (int j = 0; j < 4; j++)
                C[row * 1024 + n0 + wn + j * 16 + r15] = f2bf(acc[i][j][rr]);
        }
}

// ---------------------------------------------------------------------------
// Fused sigmoid attention v4: 32x32x16 MFMA, P stays in registers.
// Grid (32, 16, 2): x = qtile(0..15) | kh<<4; y=head; z=batch.
// 4 waves x 32 q-rows. LDS: Qs 16K + Ks 8K + Vs 8K = 32 KB.
// S^T = K·Q^T (C: col=q=lane&31, row k = (reg&3)+8*(reg>>2)+4*(lane>>5));
// C-layout -> PV A-layout via shfl_xor(32) + cndmask (no LDS round-trip).
// ---------------------------------------------------------------------------
__device__ __forceinline__ bf16x8 frag64(const u16* base, int row, int kidx) {
    return *(const bf16x8*)(base + row * 64 + ((kidx ^ (row & 7)) * 8));
}

__global__ __launch_bounds__(256, 4) void attn_sigmoid_v4(const u16* __restrict__ q,
                                                          const u16* __restrict__ k,
                                                          const u16* __restrict__ vt,
                                                          u16* __restrict__ ctx0,
                                                          u16* __restrict__ ctx1) {
    __shared__ __attribute__((aligned(16))) u16 Qs[128 * 64];
    __shared__ __attribute__((aligned(16))) u16 Ks[64 * 64];
    __shared__ __attribute__((aligned(16))) u16 Vs[64 * 64];
    const int tid = threadIdx.x;
    const int lane = tid & 63;
    const int wave = tid >> 6;
    const int l31 = lane & 31;
    const int h = lane >> 5;
    const int q0 = (blockIdx.x & 15) * 128;
    const int kh = blockIdx.x >> 4;
    const int hd = blockIdx.y;
    const int b = blockIdx.z;
    const int bh = b * 16 + hd;
    u16* ctx = kh ? ctx1 : ctx0;

    const int lr0 = lane >> 3;
    const int lc0 = lane & 7;
    {   // stage Q tile 128x64
#pragma unroll
        for (int i = 0; i < 4; i++) {
            int s = wave * 4 + i;
            int row = s * 8 + lr0;
            int c = lc0 ^ (row & 7);
            gload16(q + (size_t)(b * 2048 + q0 + row) * 1024 + hd * 64 + c * 8, Qs + s * 512);
        }
    }
    __syncthreads();
    // hoist Q B-frags (loop-invariant): B[d][n=q], lane n = wave*32+l31
    bf16x8 qB[4];
#pragma unroll
    for (int dblk = 0; dblk < 4; dblk++)
        qB[dblk] = frag64(Qs, wave * 32 + l31, dblk * 2 + h);

    f32x16 accO[2];
#pragma unroll
    for (int dt = 0; dt < 2; dt++)
#pragma unroll
        for (int r = 0; r < 16; r++) accO[dt][r] = 0.f;

    const int kbeg = kh * 1024;
    for (int kc = kbeg; kc < kbeg + 1024; kc += 64) {
        __syncthreads();
#pragma unroll
        for (int i = 0; i < 2; i++) {
            int s = wave * 2 + i;
            int row = s * 8 + lr0;
            int c = lc0 ^ (row & 7);
            gload16(k + (size_t)(b * 2048 + kc + row) * 1024 + hd * 64 + c * 8, Ks + s * 512);
            gload16(vt + (size_t)(bh * 64 + row) * 2048 + kc + c * 8, Vs + s * 512);
        }
        __syncthreads();

        // S^T: two 32k x 32q tiles, contraction over d=64 (4 x K=16)
        f32x16 accS[2];
#pragma unroll
        for (int mt = 0; mt < 2; mt++) {
#pragma unroll
            for (int r = 0; r < 16; r++) accS[mt][r] = 0.f;
#pragma unroll
            for (int dblk = 0; dblk < 4; dblk++) {
                bf16x8 aK = frag64(Ks, mt * 32 + l31, dblk * 2 + h);
                accS[mt] = __builtin_amdgcn_mfma_f32_32x32x16_bf16(aK, qB[dblk], accS[mt], 0, 0, 0);
            }
        }

        // sigmoid + pack to bf16 pairs: group g regs 4g..4g+3 (k = 8g+4h..+3)
        u32 pg[2][4][2];
#pragma unroll
        for (int mt = 0; mt < 2; mt++)
#pragma unroll
            for (int g = 0; g < 4; g++) {
                float p[4];
#pragma unroll
                for (int e = 0; e < 4; e++) {
                    float t = __builtin_fmaf(accS[mt][g * 4 + e], NLOG2E, BIAS_L2E);
                    float u = __builtin_amdgcn_exp2f(t);
                    p[e] = __builtin_amdgcn_rcpf(1.0f + u);
                }
                pg[mt][g][0] = pk_hi(p[0], p[1]);
                pg[mt][g][1] = pk_hi(p[2], p[3]);
            }

        // PV: build A-frags via shfl_xor(32), accumulate O (2 d-tiles)
#pragma unroll
        for (int mt = 0; mt < 2; mt++)
#pragma unroll
            for (int kblk = 0; kblk < 2; kblk++) {
                int glo = kblk * 2, ghi = kblk * 2 + 1;
                u32 x0 = (u32)__shfl_xor((int)pg[mt][glo][0], 32, 64);
                u32 x1 = (u32)__shfl_xor((int)pg[mt][glo][1], 32, 64);
                u32 y0 = (u32)__shfl_xor((int)pg[mt][ghi][0], 32, 64);
                u32 y1 = (u32)__shfl_xor((int)pg[mt][ghi][1], 32, 64);
                u32x4 fr;
                fr[0] = h ? y0 : pg[mt][glo][0];
                fr[1] = h ? y1 : pg[mt][glo][1];
                fr[2] = h ? pg[mt][ghi][0] : x0;
                fr[3] = h ? pg[mt][ghi][1] : x1;
                bf16x8 aP = __builtin_bit_cast(bf16x8, fr);
#pragma unroll
                for (int dt = 0; dt < 2; dt++) {
                    bf16x8 bV = frag64(Vs, dt * 32 + l31, mt * 4 + kblk * 2 + h);
                    accO[dt] = __builtin_amdgcn_mfma_f32_32x32x16_bf16(aP, bV, accO[dt], 0, 0, 0);
                }
            }
    }

    // epilogue: C row = (r&3)+8*(r>>2)+4h (q offset), col = dt*32+l31 (d)
#pragma unroll
    for (int dt = 0; dt < 2; dt++)
#pragma unroll
        for (int r = 0; r < 16; r++) {
            int qrow = q0 + wave * 32 + (r & 3) + 8 * (r >> 2) + 4 * h;
            ctx[(size_t)(b * 2048 + qrow) * 1024 + hd * 64 + dt * 32 + l31] = f2bf(accO[dt][r]);
        }
}

// ctx = ctx0 + ctx1 (bf16), 8 elems/thread
__global__ __launch_bounds__(256) void ctx_merge(const u16* __restrict__ a, const u16* __restrict__ b,
                                                 u16* __restrict__ c) {
    size_t i = ((size_t)blockIdx.x * 256 + threadIdx.x) * 8;
    u16x8 av = *(const u16x8*)(a + i);
    u16x8 bv = *(const u16x8*)(b + i);
    u16x8 o;
#pragma unroll
    for (int e = 0; e < 8; e++) o[e] = f2bf(bf2f(av[e]) + bf2f(bv[e]));
    *(u16x8*)(c + i) = o;
}

// ---------------------------------------------------------------------------
// V transpose: vb[4096,1024] -> vt[(b*16+h)*64+d][2048]
// ---------------------------------------------------------------------------
__global__ __launch_bounds__(256) void transpose_v(const u16* __restrict__ vb, u16* __restrict__ vt) {
    __shared__ u16 T[64 * 72];
    const int kt = blockIdx.x;
    const int bh = blockIdx.y;
    const int b = bh >> 4, h = bh & 15;
    const int tid = threadIdx.x;
    const int sr = tid >> 2, sc = (tid & 3) * 16;
    const u16* src = vb + (size_t)(b * 2048 + kt * 64 + sr) * 1024 + h * 64 + sc;
    *(u16x8*)&T[sr * 72 + sc] = *(const u16x8*)src;
    *(u16x8*)&T[sr * 72 + sc + 8] = *(const u16x8*)(src + 8);
    __syncthreads();
    u16x8 o0, o1;
#pragma unroll
    for (int i = 0; i < 8; i++) o0[i] = T[(sc + i) * 72 + sr];
#pragma unroll
    for (int i = 0; i < 8; i++) o1[i] = T[(sc + 8 + i) * 72 + sr];
    u16* dst = vt + (size_t)(bh * 64 + sr) * 2048 + kt * 64 + sc;
    *(u16x8*)dst = o0;
    *(u16x8*)(dst + 8) = o1;
}

// ---------------------------------------------------------------------------
// Row LayerNorm over D=1024 (fp32 in -> bf16 out)
// ---------------------------------------------------------------------------
__global__ __launch_bounds__(256) void ln_rows_bf16(const float* __restrict__ x,
                                                    const float* __restrict__ sc,
                                                    const float* __restrict__ bs,
                                                    u16* __restrict__ y) {
    __shared__ float s1buf[4], s2buf[4];
    const int row = blockIdx.x;
    const int tid = threadIdx.x;
    const size_t base = (size_t)row * 1024 + tid * 4;
    const float4 xv = *(const float4*)(x + base);
    float s1 = xv.x + xv.y + xv.z + xv.w;
    float s2 = xv.x * xv.x + xv.y * xv.y + xv.z * xv.z + xv.w * xv.w;
    int lane = tid & 63, wave = tid >> 6;
#pragma unroll
    for (int off = 32; off > 0; off >>= 1) {
        s1 += __shfl_down(s1, off, 64);
        s2 += __shfl_down(s2, off, 64);
    }
    if (lane == 0) { s1buf[wave] = s1; s2buf[wave] = s2; }
    __syncthreads();
    s1 = s1buf[0] + s1buf[1] + s1buf[2] + s1buf[3];
    s2 = s2buf[0] + s2buf[1] + s2buf[2] + s2buf[3];
    float mu = s1 * (1.0f / 1024.0f);
    float var = s2 * (1.0f / 1024.0f) - mu * mu;
    float rs = rsqrtf(var + LN_EPS);
    const float4 scv = *(const float4*)(sc + tid * 4);
    const float4 bsv = *(const float4*)(bs + tid * 4);
    u16x4 o;
    o[0] = f2bf((xv.x - mu) * rs * scv.x + bsv.x);
    o[1] = f2bf((xv.y - mu) * rs * scv.y + bsv.y);
    o[2] = f2bf((xv.z - mu) * rs * scv.z + bsv.z);
    o[3] = f2bf((xv.w - mu) * rs * scv.w + bsv.w);
    *(u16x4*)(y + base) = o;
}

// ---------------------------------------------------------------------------
// Final: out = LN(resid + gamma*(o0+o1)) (fp32, bf16 partials)
// ---------------------------------------------------------------------------
__global__ __launch_bounds__(256) void final_ln(const float* __restrict__ resid,
                                                const u16* __restrict__ o0,
                                                const u16* __restrict__ o1,
                                                const float* __restrict__ gamma,
                                                const float* __restrict__ sc,
                                                const float* __restrict__ bs,
                                                float* __restrict__ out) {
    __shared__ float s1buf[4], s2buf[4];
    const int row = blockIdx.x;
    const int tid = threadIdx.x;
    const size_t base = (size_t)row * 1024 + tid * 4;
    float4 rv = *(const float4*)(resid + base);
    u16x4 p0 = *(const u16x4*)(o0 + base);
    u16x4 p1 = *(const u16x4*)(o1 + base);
    float4 gv = *(const float4*)(gamma + tid * 4);
    float4 xv;
    xv.x = rv.x + gv.x * (bf2f(p0[0]) + bf2f(p1[0]));
    xv.y = rv.y + gv.y * (bf2f(p0[1]) + bf2f(p1[1]));
    xv.z = rv.z + gv.z * (bf2f(p0[2]) + bf2f(p1[2]));
    xv.w = rv.w + gv.w * (bf2f(p0[3]) + bf2f(p1[3]));
    float s1 = xv.x + xv.y + xv.z + xv.w;
    float s2 = xv.x * xv.x + xv.y * xv.y + xv.z * xv.z + xv.w * xv.w;
    int lane = tid & 63, wave = tid >> 6;
#pragma unroll
    for (int off = 32; off > 0; off >>= 1) {
        s1 += __shfl_down(s1, off, 64);
        s2 += __shfl_down(s2, off, 64);
    }
    if (lane == 0) { s1buf[wave] = s1; s2buf[wave] = s2; }
    __syncthreads();
    s1 = s1buf[0] + s1buf[1] + s1buf[2] + s1buf[3];
    s2 = s2buf[0] + s2buf[1] + s2buf[2] + s2buf[3];
    float mu = s1 * (1.0f / 1024.0f);
    float var = s2 * (1.0f / 1024.0f) - mu * mu;
    float rs = rsqrtf(var + LN_EPS);
    const float4 scv = *(const float4*)(sc + tid * 4);
    const float4 bsv = *(const float4*)(bs + tid * 4);
    float4 o;
    o.x = (xv.x - mu) * rs * scv.x + bsv.x;
    o.y = (xv.y - mu) * rs * scv.y + bsv.y;
    o.z = (xv.z - mu) * rs * scv.z + bsv.z;
    o.w = (xv.w - mu) * rs * scv.w + bsv.w;
    *(float4*)(out + base) = o;
}

// all fp32->bf16 converts in one launch: 4 weights (4M elems) + key_feats (2M)
__global__ __launch_bounds__(256) void conv_all(const float* __restrict__ w0, const float* __restrict__ w1,
                                                const float* __restrict__ w2, const float* __restrict__ w3,
                                                const float* __restrict__ kf,
                                                u16* __restrict__ wdst, u16* __restrict__ kdst) {
    size_t e = ((size_t)blockIdx.x * 256 + threadIdx.x) * 4;
    const float* src;
    u16* dst;
    if (e < 4194304) {
        int w = (int)(e >> 20);
        size_t off = e & 1048575;
        src = ((w == 0) ? w0 : (w == 1) ? w1 : (w == 2) ? w2 : w3) + off;
        dst = wdst + e;
    } else {
        size_t off = e - 4194304;
        src = kf + off;
        dst = kdst + off;
    }
    float4 xv = *(const float4*)src;
    u16x4 o;
    o[0] = f2bf(xv.x);
    o[1] = f2bf(xv.y);
    o[2] = f2bf(xv.z);
    o[3] = f2bf(xv.w);
    *(u16x4*)dst = o;
}

extern "C" void kernel_launch(void* const* d_in, const int* in_sizes, int n_in,
                              void* d_out, int out_size, void* d_ws, size_t ws_size,
                              hipStream_t stream) {
    const float* qf    = (const float*)d_in[0];
    const float* kf    = (const float*)d_in[1];
    const float* Wq    = (const float*)d_in[2];
    const float* Wk    = (const float*)d_in[3];
    const float* Wv    = (const float*)d_in[4];
    const float* Wo    = (const float*)d_in[5];
    const float* qn_s  = (const float*)d_in[6];
    const float* qn_b  = (const float*)d_in[7];
    const float* kn_s  = (const float*)d_in[8];
    const float* kn_b  = (const float*)d_in[9];
    const float* lnq_s = (const float*)d_in[10];
    const float* lnq_b = (const float*)d_in[11];
    const float* lno_s = (const float*)d_in[12];
    const float* lno_b = (const float*)d_in[13];
    const float* gamma = (const float*)d_in[14];
    float* out = (float*)d_out;

    char* ws = (char*)d_ws;
    const size_t MB = 1024 * 1024;
    u16* Wqb   = (u16*)(ws + 0 * MB);   // 4 weights contiguous, 8 MB
    u16* Wkb   = (u16*)(ws + 2 * MB);
    u16* Wvb   = (u16*)(ws + 4 * MB);
    u16* Wob   = (u16*)(ws + 6 * MB);
    u16* xq    = (u16*)(ws + 8 * MB);    // dead after gemm_qkv
    u16* ctx   = (u16*)(ws + 8 * MB);    // reuse xq (ctx_merge out)
    u16* keyb  = (u16*)(ws + 16 * MB);   // dead after gemm_qkv
    u16* opre0 = (u16*)(ws + 16 * MB);   // reuse keyb (gemm_o out)
    u16* qln   = (u16*)(ws + 24 * MB);   // dead after attn
    u16* opre1 = (u16*)(ws + 24 * MB);   // reuse qln (gemm_o out)
    u16* kln   = (u16*)(ws + 32 * MB);   // dead after attn
    u16* vb    = (u16*)(ws + 40 * MB);   // dead after transpose_v
    u16* ctx1  = (u16*)(ws + 40 * MB);   // reuse vb (attn out)
    u16* vt    = (u16*)(ws + 48 * MB);   // dead after attn
    u16* ctx0  = (u16*)(ws + 56 * MB);

    conv_all<<<dim3(6144), 256, 0, stream>>>(Wq, Wk, Wv, Wo, kf, Wqb, keyb);
    ln_rows_bf16<<<dim3(4096), 256, 0, stream>>>(qf, lnq_s, lnq_b, xq);

    gemm_qkv<<<dim3(32, 8, 3), 256, 0, stream>>>(xq, keyb, Wqb, Wkb, Wvb,
                                                 qn_s, qn_b, kn_s, kn_b, qln, kln, vb);

    transpose_v<<<dim3(32, 32), 256, 0, stream>>>(vb, vt);

    attn_sigmoid_v4<<<dim3(32, 16, 2), 256, 0, stream>>>(qln, kln, vt, ctx0, ctx1);
    ctx_merge<<<dim3(2048), 256, 0, stream>>>(ctx0, ctx1, ctx);

    gemm_o<<<dim3(32, 8, 2), 256, 0, stream>>>(ctx, Wob, opre0, opre1);
    final_ln<<<dim3(4096), 256, 0, stream>>>(qf, opre0, opre1, gamma, lno_s, lno_b, out);
}

// Round 9
// 249.425 us; speedup vs baseline: 1.0048x; 1.0048x over previous
//
#include <hip/hip_runtime.h>

typedef unsigned short u16;
typedef unsigned int u32;
typedef __bf16 bf16x8 __attribute__((ext_vector_type(8)));
typedef float f32x4 __attribute__((ext_vector_type(4)));
typedef float f32x16 __attribute__((ext_vector_type(16)));
typedef u16 u16x8 __attribute__((ext_vector_type(8)));
typedef u16 u16x4 __attribute__((ext_vector_type(4)));
typedef u32 u32x4 __attribute__((ext_vector_type(4)));

#define LN_EPS 1e-5f
#define SIG_SCALE_F 0.35355339059327379f /* 64^-0.25 */
#define NLOG2E -1.4426950408889634f
#define BIAS_L2E 4.328085122666891f /* 3*log2(e) */

__device__ __forceinline__ u16 f2bf(float f) {
    u32 u = __builtin_bit_cast(u32, f);
    u32 r = u + 0x7fffu + ((u >> 16) & 1u);
    return (u16)(r >> 16);
}
__device__ __forceinline__ float bf2f(u16 v) {
    return __builtin_bit_cast(float, (u32)v << 16);
}
// pack high-16s of two f32 (truncating bf16 cvt, 1 v_perm): low16=a, high16=b
__device__ __forceinline__ u32 pk_hi(float a, float b) {
    return __builtin_amdgcn_perm(__builtin_bit_cast(u32, b), __builtin_bit_cast(u32, a),
                                 0x07060302u);
}

// async global->LDS, 16B per lane; lds base wave-uniform (HW adds lane*16)
__device__ __forceinline__ void gload16(const u16* g, u16* lds) {
    __builtin_amdgcn_global_load_lds(
        (const __attribute__((address_space(1))) u32*)g,
        (__attribute__((address_space(3))) u32*)lds, 16, 0, 0);
}

// ---------------------------------------------------------------------------
// GEMM core: acc[4][4] += A[M,K] @ B[N,K]^T 128x128 tile, BK=32,
// global_load_lds staging, XOR-swizzled LDS (64B rows, chunk c^=row&3).
// ---------------------------------------------------------------------------
__device__ __forceinline__ void gemm_core(f32x4 acc[4][4],
                                          const u16* __restrict__ A, const u16* __restrict__ B,
                                          int Kiter, int lda, int ldb,
                                          long m0, long n0, u16* As, u16* Bs) {
    const int tid = threadIdx.x;
    const int lane = tid & 63;
    const int wave = tid >> 6;
    const int r15 = lane & 15;
    const int qd = lane >> 4;
    const int wm = (wave >> 1) * 64;
    const int wn = (wave & 1) * 64;

    const int srow = wave * 16 + (lane >> 2);
    const int c0 = (lane & 3) ^ (srow & 3);
    const u16* Ap0 = A + (m0 + srow) * lda + c0 * 8;
    const u16* Ap1 = A + (m0 + srow + 64) * lda + c0 * 8;
    const u16* Bp0 = B + (n0 + srow) * ldb + c0 * 8;
    const u16* Bp1 = B + (n0 + srow + 64) * ldb + c0 * 8;
    u16* As0 = As + wave * 512;
    u16* As1 = As + (wave + 4) * 512;
    u16* Bs0 = Bs + wave * 512;
    u16* Bs1 = Bs + (wave + 4) * 512;

    for (int kt = 0; kt < Kiter; kt += 32) {
        __syncthreads();
        gload16(Ap0 + kt, As0);
        gload16(Ap1 + kt, As1);
        gload16(Bp0 + kt, Bs0);
        gload16(Bp1 + kt, Bs1);
        __syncthreads();
        bf16x8 af[4], bfr[4];
#pragma unroll
        for (int i = 0; i < 4; i++) {
            int row = wm + i * 16 + r15;
            af[i] = *(const bf16x8*)(As + row * 32 + ((qd ^ (row & 3)) * 8));
        }
#pragma unroll
        for (int j = 0; j < 4; j++) {
            int row = wn + j * 16 + r15;
            bfr[j] = *(const bf16x8*)(Bs + row * 32 + ((qd ^ (row & 3)) * 8));
        }
#pragma unroll
        for (int i = 0; i < 4; i++)
#pragma unroll
            for (int j = 0; j < 4; j++)
                acc[i][j] = __builtin_amdgcn_mfma_f32_16x16x32_bf16(af[i], bfr[j], acc[i][j], 0, 0, 0);
    }
}

// ---------------------------------------------------------------------------
// Fused q/k/v projections with per-head LayerNorm epilogue for q,k.
// grid (32, 8, 3). Wave's 64-col span == one head; stats via shfl over r15.
// ---------------------------------------------------------------------------
__global__ __launch_bounds__(256) void gemm_qkv(const u16* __restrict__ xq, const u16* __restrict__ keyb,
                                                const u16* __restrict__ Wqb, const u16* __restrict__ Wkb,
                                                const u16* __restrict__ Wvb,
                                                const float* __restrict__ qns, const float* __restrict__ qnb,
                                                const float* __restrict__ kns, const float* __restrict__ knb,
                                                u16* __restrict__ qln, u16* __restrict__ kln,
                                                u16* __restrict__ vb) {
    __shared__ __attribute__((aligned(16))) u16 As[128 * 32];
    __shared__ __attribute__((aligned(16))) u16 Bs[128 * 32];
    const int z = blockIdx.z;
    const u16* A = (z == 0) ? xq : keyb;
    const u16* B = (z == 0) ? Wqb : ((z == 1) ? Wkb : Wvb);
    u16* C = (z == 0) ? qln : ((z == 1) ? kln : vb);
    const long m0 = (long)blockIdx.x * 128;
    const long n0 = (long)blockIdx.y * 128;

    f32x4 acc[4][4];
#pragma unroll
    for (int i = 0; i < 4; i++)
#pragma unroll
        for (int j = 0; j < 4; j++) acc[i][j] = (f32x4){0.f, 0.f, 0.f, 0.f};

    gemm_core(acc, A, B, 1024, 1024, 1024, m0, n0, As, Bs);

    const int lane = threadIdx.x & 63;
    const int wave = threadIdx.x >> 6;
    const int r15 = lane & 15;
    const int qd = lane >> 4;
    const int wm = (wave >> 1) * 64;
    const int wn = (wave & 1) * 64;

    if (z <= 1) {
        const float* sc_ = (z == 0) ? qns : kns;
        const float* bs_ = (z == 0) ? qnb : knb;
        float scl[4], bia[4];
#pragma unroll
        for (int j = 0; j < 4; j++) {
            scl[j] = sc_[j * 16 + r15] * SIG_SCALE_F;
            bia[j] = bs_[j * 16 + r15] * SIG_SCALE_F;
        }
#pragma unroll
        for (int i = 0; i < 4; i++) {
#pragma unroll
            for (int rr = 0; rr < 4; rr++) {
                float a0 = acc[i][0][rr], a1 = acc[i][1][rr], a2 = acc[i][2][rr], a3 = acc[i][3][rr];
                float s1 = (a0 + a1) + (a2 + a3);
                float s2 = __builtin_fmaf(a3, a3,
                           __builtin_fmaf(a2, a2, __builtin_fmaf(a1, a1, a0 * a0)));
#pragma unroll
                for (int off = 1; off <= 8; off <<= 1) {
                    s1 += __shfl_xor(s1, off, 64);
                    s2 += __shfl_xor(s2, off, 64);
                }
                float mu = s1 * (1.0f / 64.0f);
                float var = __builtin_fmaf(-mu, mu, s2 * (1.0f / 64.0f));
                float rs = rsqrtf(var + LN_EPS);
                long row = m0 + wm + i * 16 + qd * 4 + rr;
#pragma unroll
                for (int j = 0; j < 4; j++) {
                    long col = n0 + wn + j * 16 + r15;
                    float o = __builtin_fmaf((acc[i][j][rr] - mu) * rs, scl[j], bia[j]);
                    C[row * 1024 + col] = f2bf(o);
                }
            }
        }
    } else {
#pragma unroll
        for (int i = 0; i < 4; i++)
#pragma unroll
            for (int rr = 0; rr < 4; rr++) {
                long row = m0 + wm + i * 16 + qd * 4 + rr;
#pragma unroll
                for (int j = 0; j < 4; j++)
                    C[row * 1024 + n0 + wn + j * 16 + r15] = f2bf(acc[i][j][rr]);
            }
    }
}

// output projection, split-K=4: grid (32, 8, 4), bf16 partials (4/CU occupancy)
__global__ __launch_bounds__(256) void gemm_o(const u16* __restrict__ ctx, const u16* __restrict__ Wob,
                                              u16* __restrict__ opre) {
    __shared__ __attribute__((aligned(16))) u16 As[128 * 32];
    __shared__ __attribute__((aligned(16))) u16 Bs[128 * 32];
    const int z = blockIdx.z;
    const int koff = z * 256;
    u16* C = opre + (size_t)z * 4194304;
    const long m0 = (long)blockIdx.x * 128;
    const long n0 = (long)blockIdx.y * 128;
    f32x4 acc[4][4];
#pragma unroll
    for (int i = 0; i < 4; i++)
#pragma unroll
        for (int j = 0; j < 4; j++) acc[i][j] = (f32x4){0.f, 0.f, 0.f, 0.f};
    gemm_core(acc, ctx + koff, Wob + koff, 256, 1024, 1024, m0, n0, As, Bs);

    const int lane = threadIdx.x & 63;
    const int wave = threadIdx.x >> 6;
    const int r15 = lane & 15;
    const int qd = lane >> 4;
    const int wm = (wave >> 1) * 64;
    const int wn = (wave & 1) * 64;
#pragma unroll
    for (int i = 0; i < 4; i++)
#pragma unroll
        for (int rr = 0; rr < 4; rr++) {
            long row = m0 + wm + i * 16 + qd * 4 + rr;
#pragma unroll
            for (int j = 0; j < 4; j++)
                C[row * 1024 + n0 + wn + j * 16 + r15] = f2bf(acc[i][j][rr]);
        }
}

// ---------------------------------------------------------------------------
// Fused sigmoid attention v5: wave-level split-K, direct merged ctx write.
// Grid (32, 16, 2): x = qtile (64 q-rows); y = head; z = batch.
// 4 waves: qsub = wave&1 (32 q-rows), kh = wave>>1 (k half of 1024).
// LDS: Qs 8K + Ks 2x8K + Vs 2x8K = 40 KB -> 4 blocks/CU. Epilogue: kh=1
// partials through LDS (reusing Ks region), kh=0 sums + writes ctx.
// ---------------------------------------------------------------------------
__device__ __forceinline__ bf16x8 frag64(const u16* base, int row, int kidx) {
    return *(const bf16x8*)(base + row * 64 + ((kidx ^ (row & 7)) * 8));
}

__global__ __launch_bounds__(256, 4) void attn_sigmoid_v5(const u16* __restrict__ q,
                                                          const u16* __restrict__ k,
                                                          const u16* __restrict__ vt,
                                                          u16* __restrict__ ctx) {
    __shared__ __attribute__((aligned(16))) u16 Sh[4096 + 8192 + 8192];  // Qs | Ks[2] | Vs[2]
    u16* Qs = Sh;
    u16* Ks = Sh + 4096;
    u16* Vs = Sh + 4096 + 8192;
    float* Obuf = (float*)(Sh + 4096);  // 16 KB, overlaps Ks[2] (dead at epilogue)

    const int tid = threadIdx.x;
    const int lane = tid & 63;
    const int wave = tid >> 6;
    const int l31 = lane & 31;
    const int h = lane >> 5;
    const int qsub = wave & 1;
    const int kh = wave >> 1;
    const int q0 = blockIdx.x * 64;
    const int hd = blockIdx.y;
    const int b = blockIdx.z;
    const int bh = b * 16 + hd;

    const int lr0 = lane >> 3;
    const int lc0 = lane & 7;
    {   // stage Q tile 64x64: 8 segs, wave stages segs {2w, 2w+1}
#pragma unroll
        for (int i = 0; i < 2; i++) {
            int s = wave * 2 + i;
            int row = s * 8 + lr0;
            int c = lc0 ^ (row & 7);
            gload16(q + (size_t)(b * 2048 + q0 + row) * 1024 + hd * 64 + c * 8, Qs + s * 512);
        }
    }
    __syncthreads();
    // hoist Q B-frags: wave's 32 q-rows = qsub*32 + l31
    bf16x8 qB[4];
#pragma unroll
    for (int dblk = 0; dblk < 4; dblk++)
        qB[dblk] = frag64(Qs, qsub * 32 + l31, dblk * 2 + h);

    f32x16 accO[2];
#pragma unroll
    for (int dt = 0; dt < 2; dt++)
#pragma unroll
        for (int r = 0; r < 16; r++) accO[dt][r] = 0.f;

    u16* Ksh = Ks + kh * 4096;
    u16* Vsh = Vs + kh * 4096;
    const int kbeg = kh * 1024;
    for (int kc = kbeg; kc < kbeg + 1024; kc += 64) {
        __syncthreads();
        // stage this half's K,V chunk (64x64 each): 8 segs / 2 waves = 4 each
#pragma unroll
        for (int i = 0; i < 4; i++) {
            int s = qsub * 4 + i;
            int row = s * 8 + lr0;
            int c = lc0 ^ (row & 7);
            gload16(k + (size_t)(b * 2048 + kc + row) * 1024 + hd * 64 + c * 8, Ksh + s * 512);
            gload16(vt + (size_t)(bh * 64 + row) * 2048 + kc + c * 8, Vsh + s * 512);
        }
        __syncthreads();

        // S^T: two 32k x 32q tiles, contraction over d=64 (4 x K=16)
        f32x16 accS[2];
#pragma unroll
        for (int mt = 0; mt < 2; mt++) {
#pragma unroll
            for (int r = 0; r < 16; r++) accS[mt][r] = 0.f;
#pragma unroll
            for (int dblk = 0; dblk < 4; dblk++) {
                bf16x8 aK = frag64(Ksh, mt * 32 + l31, dblk * 2 + h);
                accS[mt] = __builtin_amdgcn_mfma_f32_32x32x16_bf16(aK, qB[dblk], accS[mt], 0, 0, 0);
            }
        }

        // sigmoid + pack to bf16 pairs: group g regs 4g..4g+3 (k = 8g+4h..+3)
        u32 pg[2][4][2];
#pragma unroll
        for (int mt = 0; mt < 2; mt++)
#pragma unroll
            for (int g = 0; g < 4; g++) {
                float p[4];
#pragma unroll
                for (int e = 0; e < 4; e++) {
                    float t = __builtin_fmaf(accS[mt][g * 4 + e], NLOG2E, BIAS_L2E);
                    float u = __builtin_amdgcn_exp2f(t);
                    p[e] = __builtin_amdgcn_rcpf(1.0f + u);
                }
                pg[mt][g][0] = pk_hi(p[0], p[1]);
                pg[mt][g][1] = pk_hi(p[2], p[3]);
            }

        // PV: build A-frags via shfl_xor(32), accumulate O (2 d-tiles)
#pragma unroll
        for (int mt = 0; mt < 2; mt++)
#pragma unroll
            for (int kblk = 0; kblk < 2; kblk++) {
                int glo = kblk * 2, ghi = kblk * 2 + 1;
                u32 x0 = (u32)__shfl_xor((int)pg[mt][glo][0], 32, 64);
                u32 x1 = (u32)__shfl_xor((int)pg[mt][glo][1], 32, 64);
                u32 y0 = (u32)__shfl_xor((int)pg[mt][ghi][0], 32, 64);
                u32 y1 = (u32)__shfl_xor((int)pg[mt][ghi][1], 32, 64);
                u32x4 fr;
                fr[0] = h ? y0 : pg[mt][glo][0];
                fr[1] = h ? y1 : pg[mt][glo][1];
                fr[2] = h ? pg[mt][ghi][0] : x0;
                fr[3] = h ? pg[mt][ghi][1] : x1;
                bf16x8 aP = __builtin_bit_cast(bf16x8, fr);
#pragma unroll
                for (int dt = 0; dt < 2; dt++) {
                    bf16x8 bV = frag64(Vsh, dt * 32 + l31, mt * 4 + kblk * 2 + h);
                    accO[dt] = __builtin_amdgcn_mfma_f32_32x32x16_bf16(aP, bV, accO[dt], 0, 0, 0);
                }
            }
    }

    // merge k-halves through LDS; kh=0 waves write final ctx
    __syncthreads();
    if (kh == 1) {
#pragma unroll
        for (int dt = 0; dt < 2; dt++)
#pragma unroll
            for (int r = 0; r < 16; r++) {
                int ql = qsub * 32 + (r & 3) + 8 * (r >> 2) + 4 * h;
                Obuf[ql * 64 + dt * 32 + l31] = accO[dt][r];
            }
    }
    __syncthreads();
    if (kh == 0) {
#pragma unroll
        for (int dt = 0; dt < 2; dt++)
#pragma unroll
            for (int r = 0; r < 16; r++) {
                int ql = qsub * 32 + (r & 3) + 8 * (r >> 2) + 4 * h;
                float s = accO[dt][r] + Obuf[ql * 64 + dt * 32 + l31];
                ctx[(size_t)(b * 2048 + q0 + ql) * 1024 + hd * 64 + dt * 32 + l31] = f2bf(s);
            }
    }
}

// ---------------------------------------------------------------------------
// V transpose: vb[4096,1024] -> vt[(b*16+h)*64+d][2048]
// ---------------------------------------------------------------------------
__global__ __launch_bounds__(256) void transpose_v(const u16* __restrict__ vb, u16* __restrict__ vt) {
    __shared__ u16 T[64 * 72];
    const int kt = blockIdx.x;
    const int bh = blockIdx.y;
    const int b = bh >> 4, h = bh & 15;
    const int tid = threadIdx.x;
    const int sr = tid >> 2, sc = (tid & 3) * 16;
    const u16* src = vb + (size_t)(b * 2048 + kt * 64 + sr) * 1024 + h * 64 + sc;
    *(u16x8*)&T[sr * 72 + sc] = *(const u16x8*)src;
    *(u16x8*)&T[sr * 72 + sc + 8] = *(const u16x8*)(src + 8);
    __syncthreads();
    u16x8 o0, o1;
#pragma unroll
    for (int i = 0; i < 8; i++) o0[i] = T[(sc + i) * 72 + sr];
#pragma unroll
    for (int i = 0; i < 8; i++) o1[i] = T[(sc + 8 + i) * 72 + sr];
    u16* dst = vt + (size_t)(bh * 64 + sr) * 2048 + kt * 64 + sc;
    *(u16x8*)dst = o0;
    *(u16x8*)(dst + 8) = o1;
}

// ---------------------------------------------------------------------------
// prep: fp32->bf16 of 4 weights (blocks 0..4095) + key_feats (4096..6143),
// then row-LN of query (blocks 6144..10239). One launch.
// ---------------------------------------------------------------------------
__global__ __launch_bounds__(256) void prep(const float* __restrict__ w0, const float* __restrict__ w1,
                                            const float* __restrict__ w2, const float* __restrict__ w3,
                                            const float* __restrict__ kf, const float* __restrict__ qf,
                                            const float* __restrict__ lnq_s, const float* __restrict__ lnq_b,
                                            u16* __restrict__ wdst, u16* __restrict__ kdst,
                                            u16* __restrict__ xq) {
    const int bx = blockIdx.x;
    const int tid = threadIdx.x;
    if (bx < 6144) {
        size_t e = ((size_t)bx * 256 + tid) * 4;
        const float* src;
        u16* dst;
        if (e < 4194304) {
            src = ((e >> 20) == 0 ? w0 : (e >> 20) == 1 ? w1 : (e >> 20) == 2 ? w2 : w3) + (e & 1048575);
            dst = wdst + e;
        } else {
            size_t off = e - 4194304;
            src = kf + off;
            dst = kdst + off;
        }
        float4 xv = *(const float4*)src;
        u16x4 o;
        o[0] = f2bf(xv.x);
        o[1] = f2bf(xv.y);
        o[2] = f2bf(xv.z);
        o[3] = f2bf(xv.w);
        *(u16x4*)dst = o;
    } else {
        __shared__ float s1buf[4], s2buf[4];
        const int row = bx - 6144;
        const size_t base = (size_t)row * 1024 + tid * 4;
        const float4 xv = *(const float4*)(qf + base);
        float s1 = xv.x + xv.y + xv.z + xv.w;
        float s2 = xv.x * xv.x + xv.y * xv.y + xv.z * xv.z + xv.w * xv.w;
        int lane = tid & 63, wave = tid >> 6;
#pragma unroll
        for (int off = 32; off > 0; off >>= 1) {
            s1 += __shfl_down(s1, off, 64);
            s2 += __shfl_down(s2, off, 64);
        }
        if (lane == 0) { s1buf[wave] = s1; s2buf[wave] = s2; }
        __syncthreads();
        s1 = s1buf[0] + s1buf[1] + s1buf[2] + s1buf[3];
        s2 = s2buf[0] + s2buf[1] + s2buf[2] + s2buf[3];
        float mu = s1 * (1.0f / 1024.0f);
        float var = s2 * (1.0f / 1024.0f) - mu * mu;
        float rs = rsqrtf(var + LN_EPS);
        const float4 scv = *(const float4*)(lnq_s + tid * 4);
        const float4 bsv = *(const float4*)(lnq_b + tid * 4);
        u16x4 o;
        o[0] = f2bf((xv.x - mu) * rs * scv.x + bsv.x);
        o[1] = f2bf((xv.y - mu) * rs * scv.y + bsv.y);
        o[2] = f2bf((xv.z - mu) * rs * scv.z + bsv.z);
        o[3] = f2bf((xv.w - mu) * rs * scv.w + bsv.w);
        *(u16x4*)(xq + base) = o;
    }
}

// ---------------------------------------------------------------------------
// Final: out = LN(resid + gamma*(o0+o1+o2+o3)) (fp32, bf16 partials)
// ---------------------------------------------------------------------------
__global__ __launch_bounds__(256) void final_ln(const float* __restrict__ resid,
                                                const u16* __restrict__ opre,
                                                const float* __restrict__ gamma,
                                                const float* __restrict__ sc,
                                                const float* __restrict__ bs,
                                                float* __restrict__ out) {
    __shared__ float s1buf[4], s2buf[4];
    const int row = blockIdx.x;
    const int tid = threadIdx.x;
    const size_t base = (size_t)row * 1024 + tid * 4;
    float4 rv = *(const float4*)(resid + base);
    u16x4 p0 = *(const u16x4*)(opre + base);
    u16x4 p1 = *(const u16x4*)(opre + 4194304 + base);
    u16x4 p2 = *(const u16x4*)(opre + 8388608 + base);
    u16x4 p3 = *(const u16x4*)(opre + 12582912 + base);
    float4 gv = *(const float4*)(gamma + tid * 4);
    float4 xv;
    xv.x = rv.x + gv.x * ((bf2f(p0[0]) + bf2f(p1[0])) + (bf2f(p2[0]) + bf2f(p3[0])));
    xv.y = rv.y + gv.y * ((bf2f(p0[1]) + bf2f(p1[1])) + (bf2f(p2[1]) + bf2f(p3[1])));
    xv.z = rv.z + gv.z * ((bf2f(p0[2]) + bf2f(p1[2])) + (bf2f(p2[2]) + bf2f(p3[2])));
    xv.w = rv.w + gv.w * ((bf2f(p0[3]) + bf2f(p1[3])) + (bf2f(p2[3]) + bf2f(p3[3])));
    float s1 = xv.x + xv.y + xv.z + xv.w;
    float s2 = xv.x * xv.x + xv.y * xv.y + xv.z * xv.z + xv.w * xv.w;
    int lane = tid & 63, wave = tid >> 6;
#pragma unroll
    for (int off = 32; off > 0; off >>= 1) {
        s1 += __shfl_down(s1, off, 64);
        s2 += __shfl_down(s2, off, 64);
    }
    if (lane == 0) { s1buf[wave] = s1; s2buf[wave] = s2; }
    __syncthreads();
    s1 = s1buf[0] + s1buf[1] + s1buf[2] + s1buf[3];
    s2 = s2buf[0] + s2buf[1] + s2buf[2] + s2buf[3];
    float mu = s1 * (1.0f / 1024.0f);
    float var = s2 * (1.0f / 1024.0f) - mu * mu;
    float rs = rsqrtf(var + LN_EPS);
    const float4 scv = *(const float4*)(sc + tid * 4);
    const float4 bsv = *(const float4*)(bs + tid * 4);
    float4 o;
    o.x = (xv.x - mu) * rs * scv.x + bsv.x;
    o.y = (xv.y - mu) * rs * scv.y + bsv.y;
    o.z = (xv.z - mu) * rs * scv.z + bsv.z;
    o.w = (xv.w - mu) * rs * scv.w + bsv.w;
    *(float4*)(out + base) = o;
}

extern "C" void kernel_launch(void* const* d_in, const int* in_sizes, int n_in,
                              void* d_out, int out_size, void* d_ws, size_t ws_size,
                              hipStream_t stream) {
    const float* qf    = (const float*)d_in[0];
    const float* kf    = (const float*)d_in[1];
    const float* Wq    = (const float*)d_in[2];
    const float* Wk    = (const float*)d_in[3];
    const float* Wv    = (const float*)d_in[4];
    const float* Wo    = (const float*)d_in[5];
    const float* qn_s  = (const float*)d_in[6];
    const float* qn_b  = (const float*)d_in[7];
    const float* kn_s  = (const float*)d_in[8];
    const float* kn_b  = (const float*)d_in[9];
    const float* lnq_s = (const float*)d_in[10];
    const float* lnq_b = (const float*)d_in[11];
    const float* lno_s = (const float*)d_in[12];
    const float* lno_b = (const float*)d_in[13];
    const float* gamma = (const float*)d_in[14];
    float* out = (float*)d_out;

    char* ws = (char*)d_ws;
    const size_t MB = 1024 * 1024;
    u16* Wqb   = (u16*)(ws + 0 * MB);   // 4 weights contiguous, 8 MB
    u16* Wkb   = (u16*)(ws + 2 * MB);
    u16* Wvb   = (u16*)(ws + 4 * MB);
    u16* Wob   = (u16*)(ws + 6 * MB);
    u16* xq    = (u16*)(ws + 8 * MB);    // dead after gemm_qkv
    u16* ctx   = (u16*)(ws + 8 * MB);    // reuse xq (attn writes merged ctx)
    u16* keyb  = (u16*)(ws + 16 * MB);   // dead after gemm_qkv
    u16* qln   = (u16*)(ws + 24 * MB);   // dead after attn
    u16* kln   = (u16*)(ws + 32 * MB);   // dead after attn
    u16* vb    = (u16*)(ws + 40 * MB);   // dead after transpose_v
    u16* vt    = (u16*)(ws + 48 * MB);   // dead after attn
    u16* opre  = (u16*)(ws + 24 * MB);   // 4 x 8 MB partials (reuse 24..56)

    prep<<<dim3(10240), 256, 0, stream>>>(Wq, Wk, Wv, Wo, kf, qf, lnq_s, lnq_b, Wqb, keyb, xq);

    gemm_qkv<<<dim3(32, 8, 3), 256, 0, stream>>>(xq, keyb, Wqb, Wkb, Wvb,
                                                 qn_s, qn_b, kn_s, kn_b, qln, kln, vb);

    transpose_v<<<dim3(32, 32), 256, 0, stream>>>(vb, vt);

    attn_sigmoid_v5<<<dim3(32, 16, 2), 256, 0, stream>>>(qln, kln, vt, ctx);

    gemm_o<<<dim3(32, 8, 4), 256, 0, stream>>>(ctx, Wob, opre);
    final_ln<<<dim3(4096), 256, 0, stream>>>(qf, opre, gamma, lno_s, lno_b, out);
}

// Round 10
// 242.733 us; speedup vs baseline: 1.0325x; 1.0276x over previous
//
#include <hip/hip_runtime.h>

typedef unsigned short u16;
typedef unsigned int u32;
typedef __bf16 bf16x8 __attribute__((ext_vector_type(8)));
typedef float f32x4 __attribute__((ext_vector_type(4)));
typedef float f32x16 __attribute__((ext_vector_type(16)));
typedef u16 u16x8 __attribute__((ext_vector_type(8)));
typedef u16 u16x4 __attribute__((ext_vector_type(4)));
typedef u32 u32x4 __attribute__((ext_vector_type(4)));

#define LN_EPS 1e-5f
#define SIG_SCALE_F 0.35355339059327379f /* 64^-0.25 */
#define NLOG2E -1.4426950408889634f
#define BIAS_L2E 4.328085122666891f /* 3*log2(e) */

__device__ __forceinline__ u16 f2bf(float f) {
    u32 u = __builtin_bit_cast(u32, f);
    u32 r = u + 0x7fffu + ((u >> 16) & 1u);
    return (u16)(r >> 16);
}
__device__ __forceinline__ float bf2f(u16 v) {
    return __builtin_bit_cast(float, (u32)v << 16);
}
// pack high-16s of two f32 (truncating bf16 cvt, 1 v_perm): low16=a, high16=b
__device__ __forceinline__ u32 pk_hi(float a, float b) {
    return __builtin_amdgcn_perm(__builtin_bit_cast(u32, b), __builtin_bit_cast(u32, a),
                                 0x07060302u);
}

// async global->LDS, 16B per lane; lds base wave-uniform (HW adds lane*16)
__device__ __forceinline__ void gload16(const u16* g, u16* lds) {
    __builtin_amdgcn_global_load_lds(
        (const __attribute__((address_space(1))) u32*)g,
        (__attribute__((address_space(3))) u32*)lds, 16, 0, 0);
}

// ---------------------------------------------------------------------------
// GEMM core: acc[4][4] += A[M,K] @ B[N,K]^T 128x128 tile, BK=32,
// global_load_lds staging, XOR-swizzled LDS (64B rows, chunk c^=row&3).
// ---------------------------------------------------------------------------
__device__ __forceinline__ void gemm_core(f32x4 acc[4][4],
                                          const u16* __restrict__ A, const u16* __restrict__ B,
                                          int Kiter, int lda, int ldb,
                                          long m0, long n0, u16* As, u16* Bs) {
    const int tid = threadIdx.x;
    const int lane = tid & 63;
    const int wave = tid >> 6;
    const int r15 = lane & 15;
    const int qd = lane >> 4;
    const int wm = (wave >> 1) * 64;
    const int wn = (wave & 1) * 64;

    const int srow = wave * 16 + (lane >> 2);
    const int c0 = (lane & 3) ^ (srow & 3);
    const u16* Ap0 = A + (m0 + srow) * lda + c0 * 8;
    const u16* Ap1 = A + (m0 + srow + 64) * lda + c0 * 8;
    const u16* Bp0 = B + (n0 + srow) * ldb + c0 * 8;
    const u16* Bp1 = B + (n0 + srow + 64) * ldb + c0 * 8;
    u16* As0 = As + wave * 512;
    u16* As1 = As + (wave + 4) * 512;
    u16* Bs0 = Bs + wave * 512;
    u16* Bs1 = Bs + (wave + 4) * 512;

    for (int kt = 0; kt < Kiter; kt += 32) {
        __syncthreads();
        gload16(Ap0 + kt, As0);
        gload16(Ap1 + kt, As1);
        gload16(Bp0 + kt, Bs0);
        gload16(Bp1 + kt, Bs1);
        __syncthreads();
        bf16x8 af[4], bfr[4];
#pragma unroll
        for (int i = 0; i < 4; i++) {
            int row = wm + i * 16 + r15;
            af[i] = *(const bf16x8*)(As + row * 32 + ((qd ^ (row & 3)) * 8));
        }
#pragma unroll
        for (int j = 0; j < 4; j++) {
            int row = wn + j * 16 + r15;
            bfr[j] = *(const bf16x8*)(Bs + row * 32 + ((qd ^ (row & 3)) * 8));
        }
#pragma unroll
        for (int i = 0; i < 4; i++)
#pragma unroll
            for (int j = 0; j < 4; j++)
                acc[i][j] = __builtin_amdgcn_mfma_f32_16x16x32_bf16(af[i], bfr[j], acc[i][j], 0, 0, 0);
    }
}

// ---------------------------------------------------------------------------
// Fused q/k/v projections. z<=1: per-head LayerNorm epilogue (wave's 64-col
// span == one head; stats via shfl over r15 bits). z==2: V written DIRECTLY
// TRANSPOSED into vt[(b*16+h)*64+d][2048] (block covers its full 2-head x
// 128-kk vt region so L2 assembles whole lines).  grid (32, 8, 3).
// ---------------------------------------------------------------------------
__global__ __launch_bounds__(256) void gemm_qkv(const u16* __restrict__ xq, const u16* __restrict__ keyb,
                                                const u16* __restrict__ Wqb, const u16* __restrict__ Wkb,
                                                const u16* __restrict__ Wvb,
                                                const float* __restrict__ qns, const float* __restrict__ qnb,
                                                const float* __restrict__ kns, const float* __restrict__ knb,
                                                u16* __restrict__ qln, u16* __restrict__ kln,
                                                u16* __restrict__ vt) {
    __shared__ __attribute__((aligned(16))) u16 As[128 * 32];
    __shared__ __attribute__((aligned(16))) u16 Bs[128 * 32];
    const int z = blockIdx.z;
    const u16* A = (z == 0) ? xq : keyb;
    const u16* B = (z == 0) ? Wqb : ((z == 1) ? Wkb : Wvb);
    const long m0 = (long)blockIdx.x * 128;
    const long n0 = (long)blockIdx.y * 128;

    f32x4 acc[4][4];
#pragma unroll
    for (int i = 0; i < 4; i++)
#pragma unroll
        for (int j = 0; j < 4; j++) acc[i][j] = (f32x4){0.f, 0.f, 0.f, 0.f};

    gemm_core(acc, A, B, 1024, 1024, 1024, m0, n0, As, Bs);

    const int lane = threadIdx.x & 63;
    const int wave = threadIdx.x >> 6;
    const int r15 = lane & 15;
    const int qd = lane >> 4;
    const int wm = (wave >> 1) * 64;
    const int wn = (wave & 1) * 64;

    if (z <= 1) {
        u16* C = (z == 0) ? qln : kln;
        const float* sc_ = (z == 0) ? qns : kns;
        const float* bs_ = (z == 0) ? qnb : knb;
        float scl[4], bia[4];
#pragma unroll
        for (int j = 0; j < 4; j++) {
            scl[j] = sc_[j * 16 + r15] * SIG_SCALE_F;
            bia[j] = bs_[j * 16 + r15] * SIG_SCALE_F;
        }
#pragma unroll
        for (int i = 0; i < 4; i++) {
#pragma unroll
            for (int rr = 0; rr < 4; rr++) {
                float a0 = acc[i][0][rr], a1 = acc[i][1][rr], a2 = acc[i][2][rr], a3 = acc[i][3][rr];
                float s1 = (a0 + a1) + (a2 + a3);
                float s2 = __builtin_fmaf(a3, a3,
                           __builtin_fmaf(a2, a2, __builtin_fmaf(a1, a1, a0 * a0)));
#pragma unroll
                for (int off = 1; off <= 8; off <<= 1) {
                    s1 += __shfl_xor(s1, off, 64);
                    s2 += __shfl_xor(s2, off, 64);
                }
                float mu = s1 * (1.0f / 64.0f);
                float var = __builtin_fmaf(-mu, mu, s2 * (1.0f / 64.0f));
                float rs = rsqrtf(var + LN_EPS);
                long row = m0 + wm + i * 16 + qd * 4 + rr;
#pragma unroll
                for (int j = 0; j < 4; j++) {
                    long col = n0 + wn + j * 16 + r15;
                    float o = __builtin_fmaf((acc[i][j][rr] - mu) * rs, scl[j], bia[j]);
                    C[row * 1024 + col] = f2bf(o);
                }
            }
        }
    } else {
        // direct transposed V write: row -> (b, kk), col -> (h, d)
#pragma unroll
        for (int i = 0; i < 4; i++)
#pragma unroll
            for (int rr = 0; rr < 4; rr++) {
                int grow = (int)(m0 + wm + i * 16 + qd * 4 + rr);
                int bb = grow >> 11;
                int kk = grow & 2047;
#pragma unroll
                for (int j = 0; j < 4; j++) {
                    int col = (int)(n0 + wn + j * 16 + r15);
                    int hh = col >> 6;
                    int dd = col & 63;
                    vt[((size_t)(bb * 16 + hh) * 64 + dd) * 2048 + kk] = f2bf(acc[i][j][rr]);
                }
            }
    }
}

// output projection, split-K=4: grid (32, 8, 4), bf16 partials (4/CU occupancy)
__global__ __launch_bounds__(256) void gemm_o(const u16* __restrict__ ctx, const u16* __restrict__ Wob,
                                              u16* __restrict__ opre) {
    __shared__ __attribute__((aligned(16))) u16 As[128 * 32];
    __shared__ __attribute__((aligned(16))) u16 Bs[128 * 32];
    const int z = blockIdx.z;
    const int koff = z * 256;
    u16* C = opre + (size_t)z * 4194304;
    const long m0 = (long)blockIdx.x * 128;
    const long n0 = (long)blockIdx.y * 128;
    f32x4 acc[4][4];
#pragma unroll
    for (int i = 0; i < 4; i++)
#pragma unroll
        for (int j = 0; j < 4; j++) acc[i][j] = (f32x4){0.f, 0.f, 0.f, 0.f};
    gemm_core(acc, ctx + koff, Wob + koff, 256, 1024, 1024, m0, n0, As, Bs);

    const int lane = threadIdx.x & 63;
    const int wave = threadIdx.x >> 6;
    const int r15 = lane & 15;
    const int qd = lane >> 4;
    const int wm = (wave >> 1) * 64;
    const int wn = (wave & 1) * 64;
#pragma unroll
    for (int i = 0; i < 4; i++)
#pragma unroll
        for (int rr = 0; rr < 4; rr++) {
            long row = m0 + wm + i * 16 + qd * 4 + rr;
#pragma unroll
            for (int j = 0; j < 4; j++)
                C[row * 1024 + n0 + wn + j * 16 + r15] = f2bf(acc[i][j][rr]);
        }
}

// ---------------------------------------------------------------------------
// Fused sigmoid attention v6: wave-level split-K + XCD-aware grid.
// Grid (16, 32, 2): x = HEAD (block id % 8 == head % 8 -> all of a head's
// blocks land on one XCD; per-XCD K/V working set ~2 MB < 4 MB L2);
// y = qtile (64 q-rows); z = batch.
// 4 waves: qsub = wave&1 (32 q-rows), kh = wave>>1 (k half of 1024).
// LDS: Qs 8K + Ks 2x8K + Vs 2x8K = 40 KB -> 4 blocks/CU. Epilogue: kh=1
// partials through LDS (reusing Ks region), kh=0 sums + writes ctx.
// ---------------------------------------------------------------------------
__device__ __forceinline__ bf16x8 frag64(const u16* base, int row, int kidx) {
    return *(const bf16x8*)(base + row * 64 + ((kidx ^ (row & 7)) * 8));
}

__global__ __launch_bounds__(256, 4) void attn_sigmoid_v6(const u16* __restrict__ q,
                                                          const u16* __restrict__ k,
                                                          const u16* __restrict__ vt,
                                                          u16* __restrict__ ctx) {
    __shared__ __attribute__((aligned(16))) u16 Sh[4096 + 8192 + 8192];  // Qs | Ks[2] | Vs[2]
    u16* Qs = Sh;
    u16* Ks = Sh + 4096;
    u16* Vs = Sh + 4096 + 8192;
    float* Obuf = (float*)(Sh + 4096);  // 16 KB, overlaps Ks[2] (dead at epilogue)

    const int tid = threadIdx.x;
    const int lane = tid & 63;
    const int wave = tid >> 6;
    const int l31 = lane & 31;
    const int h = lane >> 5;
    const int qsub = wave & 1;
    const int kh = wave >> 1;
    const int hd = blockIdx.x;         // head (XCD-aligned)
    const int q0 = blockIdx.y * 64;
    const int b = blockIdx.z;
    const int bh = b * 16 + hd;

    const int lr0 = lane >> 3;
    const int lc0 = lane & 7;
    {   // stage Q tile 64x64: 8 segs, wave stages segs {2w, 2w+1}
#pragma unroll
        for (int i = 0; i < 2; i++) {
            int s = wave * 2 + i;
            int row = s * 8 + lr0;
            int c = lc0 ^ (row & 7);
            gload16(q + (size_t)(b * 2048 + q0 + row) * 1024 + hd * 64 + c * 8, Qs + s * 512);
        }
    }
    __syncthreads();
    // hoist Q B-frags: wave's 32 q-rows = qsub*32 + l31
    bf16x8 qB[4];
#pragma unroll
    for (int dblk = 0; dblk < 4; dblk++)
        qB[dblk] = frag64(Qs, qsub * 32 + l31, dblk * 2 + h);

    f32x16 accO[2];
#pragma unroll
    for (int dt = 0; dt < 2; dt++)
#pragma unroll
        for (int r = 0; r < 16; r++) accO[dt][r] = 0.f;

    u16* Ksh = Ks + kh * 4096;
    u16* Vsh = Vs + kh * 4096;
    const int kbeg = kh * 1024;
    for (int kc = kbeg; kc < kbeg + 1024; kc += 64) {
        __syncthreads();
        // stage this half's K,V chunk (64x64 each): 8 segs / 2 waves = 4 each
#pragma unroll
        for (int i = 0; i < 4; i++) {
            int s = qsub * 4 + i;
            int row = s * 8 + lr0;
            int c = lc0 ^ (row & 7);
            gload16(k + (size_t)(b * 2048 + kc + row) * 1024 + hd * 64 + c * 8, Ksh + s * 512);
            gload16(vt + (size_t)(bh * 64 + row) * 2048 + kc + c * 8, Vsh + s * 512);
        }
        __syncthreads();

        // S^T: two 32k x 32q tiles, contraction over d=64 (4 x K=16)
        f32x16 accS[2];
#pragma unroll
        for (int mt = 0; mt < 2; mt++) {
#pragma unroll
            for (int r = 0; r < 16; r++) accS[mt][r] = 0.f;
#pragma unroll
            for (int dblk = 0; dblk < 4; dblk++) {
                bf16x8 aK = frag64(Ksh, mt * 32 + l31, dblk * 2 + h);
                accS[mt] = __builtin_amdgcn_mfma_f32_32x32x16_bf16(aK, qB[dblk], accS[mt], 0, 0, 0);
            }
        }

        // sigmoid + pack to bf16 pairs: group g regs 4g..4g+3 (k = 8g+4h..+3)
        u32 pg[2][4][2];
#pragma unroll
        for (int mt = 0; mt < 2; mt++)
#pragma unroll
            for (int g = 0; g < 4; g++) {
                float p[4];
#pragma unroll
                for (int e = 0; e < 4; e++) {
                    float t = __builtin_fmaf(accS[mt][g * 4 + e], NLOG2E, BIAS_L2E);
                    float u = __builtin_amdgcn_exp2f(t);
                    p[e] = __builtin_amdgcn_rcpf(1.0f + u);
                }
                pg[mt][g][0] = pk_hi(p[0], p[1]);
                pg[mt][g][1] = pk_hi(p[2], p[3]);
            }

        // PV: build A-frags via shfl_xor(32), accumulate O (2 d-tiles)
#pragma unroll
        for (int mt = 0; mt < 2; mt++)
#pragma unroll
            for (int kblk = 0; kblk < 2; kblk++) {
                int glo = kblk * 2, ghi = kblk * 2 + 1;
                u32 x0 = (u32)__shfl_xor((int)pg[mt][glo][0], 32, 64);
                u32 x1 = (u32)__shfl_xor((int)pg[mt][glo][1], 32, 64);
                u32 y0 = (u32)__shfl_xor((int)pg[mt][ghi][0], 32, 64);
                u32 y1 = (u32)__shfl_xor((int)pg[mt][ghi][1], 32, 64);
                u32x4 fr;
                fr[0] = h ? y0 : pg[mt][glo][0];
                fr[1] = h ? y1 : pg[mt][glo][1];
                fr[2] = h ? pg[mt][ghi][0] : x0;
                fr[3] = h ? pg[mt][ghi][1] : x1;
                bf16x8 aP = __builtin_bit_cast(bf16x8, fr);
#pragma unroll
                for (int dt = 0; dt < 2; dt++) {
                    bf16x8 bV = frag64(Vsh, dt * 32 + l31, mt * 4 + kblk * 2 + h);
                    accO[dt] = __builtin_amdgcn_mfma_f32_32x32x16_bf16(aP, bV, accO[dt], 0, 0, 0);
                }
            }
    }

    // merge k-halves through LDS; kh=0 waves write final ctx
    __syncthreads();
    if (kh == 1) {
#pragma unroll
        for (int dt = 0; dt < 2; dt++)
#pragma unroll
            for (int r = 0; r < 16; r++) {
                int ql = qsub * 32 + (r & 3) + 8 * (r >> 2) + 4 * h;
                Obuf[ql * 64 + dt * 32 + l31] = accO[dt][r];
            }
    }
    __syncthreads();
    if (kh == 0) {
#pragma unroll
        for (int dt = 0; dt < 2; dt++)
#pragma unroll
            for (int r = 0; r < 16; r++) {
                int ql = qsub * 32 + (r & 3) + 8 * (r >> 2) + 4 * h;
                float s = accO[dt][r] + Obuf[ql * 64 + dt * 32 + l31];
                ctx[(size_t)(b * 2048 + q0 + ql) * 1024 + hd * 64 + dt * 32 + l31] = f2bf(s);
            }
    }
}

// ---------------------------------------------------------------------------
// prep: fp32->bf16 of 4 weights (blocks 0..4095) + key_feats (4096..6143),
// then row-LN of query (blocks 6144..10239). One launch.
// ---------------------------------------------------------------------------
__global__ __launch_bounds__(256) void prep(const float* __restrict__ w0, const float* __restrict__ w1,
                                            const float* __restrict__ w2, const float* __restrict__ w3,
                                            const float* __restrict__ kf, const float* __restrict__ qf,
                                            const float* __restrict__ lnq_s, const float* __restrict__ lnq_b,
                                            u16* __restrict__ wdst, u16* __restrict__ kdst,
                                            u16* __restrict__ xq) {
    const int bx = blockIdx.x;
    const int tid = threadIdx.x;
    if (bx < 6144) {
        size_t e = ((size_t)bx * 256 + tid) * 4;
        const float* src;
        u16* dst;
        if (e < 4194304) {
            src = ((e >> 20) == 0 ? w0 : (e >> 20) == 1 ? w1 : (e >> 20) == 2 ? w2 : w3) + (e & 1048575);
            dst = wdst + e;
        } else {
            size_t off = e - 4194304;
            src = kf + off;
            dst = kdst + off;
        }
        float4 xv = *(const float4*)src;
        u16x4 o;
        o[0] = f2bf(xv.x);
        o[1] = f2bf(xv.y);
        o[2] = f2bf(xv.z);
        o[3] = f2bf(xv.w);
        *(u16x4*)dst = o;
    } else {
        __shared__ float s1buf[4], s2buf[4];
        const int row = bx - 6144;
        const size_t base = (size_t)row * 1024 + tid * 4;
        const float4 xv = *(const float4*)(qf + base);
        float s1 = xv.x + xv.y + xv.z + xv.w;
        float s2 = xv.x * xv.x + xv.y * xv.y + xv.z * xv.z + xv.w * xv.w;
        int lane = tid & 63, wave = tid >> 6;
#pragma unroll
        for (int off = 32; off > 0; off >>= 1) {
            s1 += __shfl_down(s1, off, 64);
            s2 += __shfl_down(s2, off, 64);
        }
        if (lane == 0) { s1buf[wave] = s1; s2buf[wave] = s2; }
        __syncthreads();
        s1 = s1buf[0] + s1buf[1] + s1buf[2] + s1buf[3];
        s2 = s2buf[0] + s2buf[1] + s2buf[2] + s2buf[3];
        float mu = s1 * (1.0f / 1024.0f);
        float var = s2 * (1.0f / 1024.0f) - mu * mu;
        float rs = rsqrtf(var + LN_EPS);
        const float4 scv = *(const float4*)(lnq_s + tid * 4);
        const float4 bsv = *(const float4*)(lnq_b + tid * 4);
        u16x4 o;
        o[0] = f2bf((xv.x - mu) * rs * scv.x + bsv.x);
        o[1] = f2bf((xv.y - mu) * rs * scv.y + bsv.y);
        o[2] = f2bf((xv.z - mu) * rs * scv.z + bsv.z);
        o[3] = f2bf((xv.w - mu) * rs * scv.w + bsv.w);
        *(u16x4*)(xq + base) = o;
    }
}

// ---------------------------------------------------------------------------
// Final: out = LN(resid + gamma*(o0+o1+o2+o3)) (fp32, bf16 partials)
// ---------------------------------------------------------------------------
__global__ __launch_bounds__(256) void final_ln(const float* __restrict__ resid,
                                                const u16* __restrict__ opre,
                                                const float* __restrict__ gamma,
                                                const float* __restrict__ sc,
                                                const float* __restrict__ bs,
                                                float* __restrict__ out) {
    __shared__ float s1buf[4], s2buf[4];
    const int row = blockIdx.x;
    const int tid = threadIdx.x;
    const size_t base = (size_t)row * 1024 + tid * 4;
    float4 rv = *(const float4*)(resid + base);
    u16x4 p0 = *(const u16x4*)(opre + base);
    u16x4 p1 = *(const u16x4*)(opre + 4194304 + base);
    u16x4 p2 = *(const u16x4*)(opre + 8388608 + base);
    u16x4 p3 = *(const u16x4*)(opre + 12582912 + base);
    float4 gv = *(const float4*)(gamma + tid * 4);
    float4 xv;
    xv.x = rv.x + gv.x * ((bf2f(p0[0]) + bf2f(p1[0])) + (bf2f(p2[0]) + bf2f(p3[0])));
    xv.y = rv.y + gv.y * ((bf2f(p0[1]) + bf2f(p1[1])) + (bf2f(p2[1]) + bf2f(p3[1])));
    xv.z = rv.z + gv.z * ((bf2f(p0[2]) + bf2f(p1[2])) + (bf2f(p2[2]) + bf2f(p3[2])));
    xv.w = rv.w + gv.w * ((bf2f(p0[3]) + bf2f(p1[3])) + (bf2f(p2[3]) + bf2f(p3[3])));
    float s1 = xv.x + xv.y + xv.z + xv.w;
    float s2 = xv.x * xv.x + xv.y * xv.y + xv.z * xv.z + xv.w * xv.w;
    int lane = tid & 63, wave = tid >> 6;
#pragma unroll
    for (int off = 32; off > 0; off >>= 1) {
        s1 += __shfl_down(s1, off, 64);
        s2 += __shfl_down(s2, off, 64);
    }
    if (lane == 0) { s1buf[wave] = s1; s2buf[wave] = s2; }
    __syncthreads();
    s1 = s1buf[0] + s1buf[1] + s1buf[2] + s1buf[3];
    s2 = s2buf[0] + s2buf[1] + s2buf[2] + s2buf[3];
    float mu = s1 * (1.0f / 1024.0f);
    float var = s2 * (1.0f / 1024.0f) - mu * mu;
    float rs = rsqrtf(var + LN_EPS);
    const float4 scv = *(const float4*)(sc + tid * 4);
    const float4 bsv = *(const float4*)(bs + tid * 4);
    float4 o;
    o.x = (xv.x - mu) * rs * scv.x + bsv.x;
    o.y = (xv.y - mu) * rs * scv.y + bsv.y;
    o.z = (xv.z - mu) * rs * scv.z + bsv.z;
    o.w = (xv.w - mu) * rs * scv.w + bsv.w;
    *(float4*)(out + base) = o;
}

extern "C" void kernel_launch(void* const* d_in, const int* in_sizes, int n_in,
                              void* d_out, int out_size, void* d_ws, size_t ws_size,
                              hipStream_t stream) {
    const float* qf    = (const float*)d_in[0];
    const float* kf    = (const float*)d_in[1];
    const float* Wq    = (const float*)d_in[2];
    const float* Wk    = (const float*)d_in[3];
    const float* Wv    = (const float*)d_in[4];
    const float* Wo    = (const float*)d_in[5];
    const float* qn_s  = (const float*)d_in[6];
    const float* qn_b  = (const float*)d_in[7];
    const float* kn_s  = (const float*)d_in[8];
    const float* kn_b  = (const float*)d_in[9];
    const float* lnq_s = (const float*)d_in[10];
    const float* lnq_b = (const float*)d_in[11];
    const float* lno_s = (const float*)d_in[12];
    const float* lno_b = (const float*)d_in[13];
    const float* gamma = (const float*)d_in[14];
    float* out = (float*)d_out;

    char* ws = (char*)d_ws;
    const size_t MB = 1024 * 1024;
    u16* Wqb   = (u16*)(ws + 0 * MB);   // 4 weights contiguous, 8 MB
    u16* Wkb   = (u16*)(ws + 2 * MB);
    u16* Wvb   = (u16*)(ws + 4 * MB);
    u16* Wob   = (u16*)(ws + 6 * MB);
    u16* xq    = (u16*)(ws + 8 * MB);    // dead after gemm_qkv
    u16* ctx   = (u16*)(ws + 8 * MB);    // reuse xq (attn writes merged ctx)
    u16* keyb  = (u16*)(ws + 16 * MB);   // dead after gemm_qkv
    u16* qln   = (u16*)(ws + 24 * MB);   // dead after attn
    u16* kln   = (u16*)(ws + 32 * MB);   // dead after attn
    u16* vt    = (u16*)(ws + 48 * MB);   // written by gemm_qkv z=2, dead after attn
    u16* opre  = (u16*)(ws + 24 * MB);   // 4 x 8 MB partials (reuse 24..56)

    prep<<<dim3(10240), 256, 0, stream>>>(Wq, Wk, Wv, Wo, kf, qf, lnq_s, lnq_b, Wqb, keyb, xq);

    gemm_qkv<<<dim3(32, 8, 3), 256, 0, stream>>>(xq, keyb, Wqb, Wkb, Wvb,
                                                 qn_s, qn_b, kn_s, kn_b, qln, kln, vt);

    attn_sigmoid_v6<<<dim3(16, 32, 2), 256, 0, stream>>>(qln, kln, vt, ctx);

    gemm_o<<<dim3(32, 8, 4), 256, 0, stream>>>(ctx, Wob, opre);
    final_ln<<<dim3(4096), 256, 0, stream>>>(qf, opre, gamma, lno_s, lno_b, out);
}

// Round 11
// 233.624 us; speedup vs baseline: 1.0727x; 1.0390x over previous
//
#include <hip/hip_runtime.h>

typedef unsigned short u16;
typedef unsigned int u32;
typedef __bf16 bf16x8 __attribute__((ext_vector_type(8)));
typedef float f32x4 __attribute__((ext_vector_type(4)));
typedef float f32x16 __attribute__((ext_vector_type(16)));
typedef u16 u16x8 __attribute__((ext_vector_type(8)));
typedef u16 u16x4 __attribute__((ext_vector_type(4)));
typedef u32 u32x4 __attribute__((ext_vector_type(4)));

#define LN_EPS 1e-5f
#define SIG_SCALE_F 0.35355339059327379f /* 64^-0.25 */
#define NLOG2E -1.4426950408889634f
#define BIAS_L2E 4.328085122666891f /* 3*log2(e) */

__device__ __forceinline__ u16 f2bf(float f) {
    u32 u = __builtin_bit_cast(u32, f);
    u32 r = u + 0x7fffu + ((u >> 16) & 1u);
    return (u16)(r >> 16);
}
__device__ __forceinline__ float bf2f(u16 v) {
    return __builtin_bit_cast(float, (u32)v << 16);
}
// pack high-16s of two f32 (truncating bf16 cvt, 1 v_perm): low16=a, high16=b
__device__ __forceinline__ u32 pk_hi(float a, float b) {
    return __builtin_amdgcn_perm(__builtin_bit_cast(u32, b), __builtin_bit_cast(u32, a),
                                 0x07060302u);
}

// async global->LDS, 16B per lane; lds base wave-uniform (HW adds lane*16)
__device__ __forceinline__ void gload16(const u16* g, u16* lds) {
    __builtin_amdgcn_global_load_lds(
        (const __attribute__((address_space(1))) u32*)g,
        (__attribute__((address_space(3))) u32*)lds, 16, 0, 0);
}

// ---------------------------------------------------------------------------
// GEMM core: acc[4][4] += A[M,K] @ B[N,K]^T 128x128 tile, BK=32,
// global_load_lds staging, XOR-swizzled LDS (64B rows, chunk c^=row&3).
// ---------------------------------------------------------------------------
__device__ __forceinline__ void gemm_core(f32x4 acc[4][4],
                                          const u16* __restrict__ A, const u16* __restrict__ B,
                                          int Kiter, int lda, int ldb,
                                          long m0, long n0, u16* As, u16* Bs) {
    const int tid = threadIdx.x;
    const int lane = tid & 63;
    const int wave = tid >> 6;
    const int r15 = lane & 15;
    const int qd = lane >> 4;
    const int wm = (wave >> 1) * 64;
    const int wn = (wave & 1) * 64;

    const int srow = wave * 16 + (lane >> 2);
    const int c0 = (lane & 3) ^ (srow & 3);
    const u16* Ap0 = A + (m0 + srow) * lda + c0 * 8;
    const u16* Ap1 = A + (m0 + srow + 64) * lda + c0 * 8;
    const u16* Bp0 = B + (n0 + srow) * ldb + c0 * 8;
    const u16* Bp1 = B + (n0 + srow + 64) * ldb + c0 * 8;
    u16* As0 = As + wave * 512;
    u16* As1 = As + (wave + 4) * 512;
    u16* Bs0 = Bs + wave * 512;
    u16* Bs1 = Bs + (wave + 4) * 512;

    for (int kt = 0; kt < Kiter; kt += 32) {
        __syncthreads();
        gload16(Ap0 + kt, As0);
        gload16(Ap1 + kt, As1);
        gload16(Bp0 + kt, Bs0);
        gload16(Bp1 + kt, Bs1);
        __syncthreads();
        bf16x8 af[4], bfr[4];
#pragma unroll
        for (int i = 0; i < 4; i++) {
            int row = wm + i * 16 + r15;
            af[i] = *(const bf16x8*)(As + row * 32 + ((qd ^ (row & 3)) * 8));
        }
#pragma unroll
        for (int j = 0; j < 4; j++) {
            int row = wn + j * 16 + r15;
            bfr[j] = *(const bf16x8*)(Bs + row * 32 + ((qd ^ (row & 3)) * 8));
        }
#pragma unroll
        for (int i = 0; i < 4; i++)
#pragma unroll
            for (int j = 0; j < 4; j++)
                acc[i][j] = __builtin_amdgcn_mfma_f32_16x16x32_bf16(af[i], bfr[j], acc[i][j], 0, 0, 0);
    }
}

// ---------------------------------------------------------------------------
// Fused q/k/v projections. z<=1: per-head LayerNorm epilogue. z==2: V written
// directly transposed into vt[(b*16+h)*64+d][2048]. grid (32, 8, 3).
// launch_bounds(256,3): cap VGPR so 3 blocks/CU stay resident.
// ---------------------------------------------------------------------------
__global__ __launch_bounds__(256, 3) void gemm_qkv(const u16* __restrict__ xq, const u16* __restrict__ keyb,
                                                   const u16* __restrict__ Wqb, const u16* __restrict__ Wkb,
                                                   const u16* __restrict__ Wvb,
                                                   const float* __restrict__ qns, const float* __restrict__ qnb,
                                                   const float* __restrict__ kns, const float* __restrict__ knb,
                                                   u16* __restrict__ qln, u16* __restrict__ kln,
                                                   u16* __restrict__ vt) {
    __shared__ __attribute__((aligned(16))) u16 As[128 * 32];
    __shared__ __attribute__((aligned(16))) u16 Bs[128 * 32];
    const int z = blockIdx.z;
    const u16* A = (z == 0) ? xq : keyb;
    const u16* B = (z == 0) ? Wqb : ((z == 1) ? Wkb : Wvb);
    const long m0 = (long)blockIdx.x * 128;
    const long n0 = (long)blockIdx.y * 128;

    f32x4 acc[4][4];
#pragma unroll
    for (int i = 0; i < 4; i++)
#pragma unroll
        for (int j = 0; j < 4; j++) acc[i][j] = (f32x4){0.f, 0.f, 0.f, 0.f};

    gemm_core(acc, A, B, 1024, 1024, 1024, m0, n0, As, Bs);

    const int lane = threadIdx.x & 63;
    const int wave = threadIdx.x >> 6;
    const int r15 = lane & 15;
    const int qd = lane >> 4;
    const int wm = (wave >> 1) * 64;
    const int wn = (wave & 1) * 64;

    if (z <= 1) {
        u16* C = (z == 0) ? qln : kln;
        const float* sc_ = (z == 0) ? qns : kns;
        const float* bs_ = (z == 0) ? qnb : knb;
        float scl[4], bia[4];
#pragma unroll
        for (int j = 0; j < 4; j++) {
            scl[j] = sc_[j * 16 + r15] * SIG_SCALE_F;
            bia[j] = bs_[j * 16 + r15] * SIG_SCALE_F;
        }
#pragma unroll
        for (int i = 0; i < 4; i++) {
#pragma unroll
            for (int rr = 0; rr < 4; rr++) {
                float a0 = acc[i][0][rr], a1 = acc[i][1][rr], a2 = acc[i][2][rr], a3 = acc[i][3][rr];
                float s1 = (a0 + a1) + (a2 + a3);
                float s2 = __builtin_fmaf(a3, a3,
                           __builtin_fmaf(a2, a2, __builtin_fmaf(a1, a1, a0 * a0)));
#pragma unroll
                for (int off = 1; off <= 8; off <<= 1) {
                    s1 += __shfl_xor(s1, off, 64);
                    s2 += __shfl_xor(s2, off, 64);
                }
                float mu = s1 * (1.0f / 64.0f);
                float var = __builtin_fmaf(-mu, mu, s2 * (1.0f / 64.0f));
                float rs = rsqrtf(var + LN_EPS);
                long row = m0 + wm + i * 16 + qd * 4 + rr;
#pragma unroll
                for (int j = 0; j < 4; j++) {
                    long col = n0 + wn + j * 16 + r15;
                    float o = __builtin_fmaf((acc[i][j][rr] - mu) * rs, scl[j], bia[j]);
                    C[row * 1024 + col] = f2bf(o);
                }
            }
        }
    } else {
        // direct transposed V write: row -> (b, kk), col -> (h, d)
#pragma unroll
        for (int i = 0; i < 4; i++)
#pragma unroll
            for (int rr = 0; rr < 4; rr++) {
                int grow = (int)(m0 + wm + i * 16 + qd * 4 + rr);
                int bb = grow >> 11;
                int kk = grow & 2047;
#pragma unroll
                for (int j = 0; j < 4; j++) {
                    int col = (int)(n0 + wn + j * 16 + r15);
                    int hh = col >> 6;
                    int dd = col & 63;
                    vt[((size_t)(bb * 16 + hh) * 64 + dd) * 2048 + kk] = f2bf(acc[i][j][rr]);
                }
            }
    }
}

// output projection, split-K=4: grid (32, 8, 4), bf16 partials (4/CU occupancy)
__global__ __launch_bounds__(256, 4) void gemm_o(const u16* __restrict__ ctx, const u16* __restrict__ Wob,
                                                 u16* __restrict__ opre) {
    __shared__ __attribute__((aligned(16))) u16 As[128 * 32];
    __shared__ __attribute__((aligned(16))) u16 Bs[128 * 32];
    const int z = blockIdx.z;
    const int koff = z * 256;
    u16* C = opre + (size_t)z * 4194304;
    const long m0 = (long)blockIdx.x * 128;
    const long n0 = (long)blockIdx.y * 128;
    f32x4 acc[4][4];
#pragma unroll
    for (int i = 0; i < 4; i++)
#pragma unroll
        for (int j = 0; j < 4; j++) acc[i][j] = (f32x4){0.f, 0.f, 0.f, 0.f};
    gemm_core(acc, ctx + koff, Wob + koff, 256, 1024, 1024, m0, n0, As, Bs);

    const int lane = threadIdx.x & 63;
    const int wave = threadIdx.x >> 6;
    const int r15 = lane & 15;
    const int qd = lane >> 4;
    const int wm = (wave >> 1) * 64;
    const int wn = (wave & 1) * 64;
#pragma unroll
    for (int i = 0; i < 4; i++)
#pragma unroll
        for (int rr = 0; rr < 4; rr++) {
            long row = m0 + wm + i * 16 + qd * 4 + rr;
#pragma unroll
            for (int j = 0; j < 4; j++)
                C[row * 1024 + n0 + wn + j * 16 + r15] = f2bf(acc[i][j][rr]);
        }
}

// ---------------------------------------------------------------------------
// Fused sigmoid attention v7: 512 threads / 8 waves, 128 q-rows per block.
// Grid (16, 16, 2): x = HEAD (XCD-pinned), y = 128-q tile, z = batch.
// Waves: qsub = wave&3 (32 q-rows each), kh = wave>>2 (k half of 1024).
// Staging per chunk: 32 segs over 8 waves (half the per-q staging of v6);
// one barrier pair serves 2x the MFMA work. LDS: Qs 16K + Ks 2x8K + Vs 2x8K
// = 48 KB -> 2 blocks/CU x 8 waves = 16 waves/CU. Epilogue: kh=1 partials
// through 32KB Obuf (overlays dead K/V LDS), kh=0 sums + writes merged ctx.
// ---------------------------------------------------------------------------
__device__ __forceinline__ bf16x8 frag64(const u16* base, int row, int kidx) {
    return *(const bf16x8*)(base + row * 64 + ((kidx ^ (row & 7)) * 8));
}

__global__ __launch_bounds__(512, 4) void attn_sigmoid_v7(const u16* __restrict__ q,
                                                          const u16* __restrict__ k,
                                                          const u16* __restrict__ vt,
                                                          u16* __restrict__ ctx) {
    __shared__ __attribute__((aligned(16))) u16 Sh[8192 + 8192 + 8192];  // Qs | Ks[2] | Vs[2]
    u16* Qs = Sh;
    u16* Ks = Sh + 8192;
    u16* Vs = Sh + 16384;
    float* Obuf = (float*)(Sh + 8192);  // 32 KB, overlays Ks+Vs (dead at epilogue)

    const int tid = threadIdx.x;
    const int lane = tid & 63;
    const int wave = tid >> 6;       // 0..7
    const int l31 = lane & 31;
    const int h = lane >> 5;
    const int qsub = wave & 3;       // 32-q-row group
    const int kh = wave >> 2;        // k half
    const int hd = blockIdx.x;       // head (XCD-aligned)
    const int q0 = blockIdx.y * 128;
    const int b = blockIdx.z;
    const int bh = b * 16 + hd;

    const int lr0 = lane >> 3;
    const int lc0 = lane & 7;
    {   // stage Q tile 128x64: 16 segs, wave stages segs {2w, 2w+1}
#pragma unroll
        for (int i = 0; i < 2; i++) {
            int s = wave * 2 + i;
            int row = s * 8 + lr0;
            int c = lc0 ^ (row & 7);
            gload16(q + (size_t)(b * 2048 + q0 + row) * 1024 + hd * 64 + c * 8, Qs + s * 512);
        }
    }
    __syncthreads();
    // hoist Q B-frags: wave's 32 q-rows = qsub*32 + l31
    bf16x8 qB[4];
#pragma unroll
    for (int dblk = 0; dblk < 4; dblk++)
        qB[dblk] = frag64(Qs, qsub * 32 + l31, dblk * 2 + h);

    f32x16 accO[2];
#pragma unroll
    for (int dt = 0; dt < 2; dt++)
#pragma unroll
        for (int r = 0; r < 16; r++) accO[dt][r] = 0.f;

    u16* Ksh = Ks + kh * 4096;
    u16* Vsh = Vs + kh * 4096;
    const int wsub = wave & 3;
    const int kbeg = kh * 1024;
    for (int kc = kbeg; kc < kbeg + 1024; kc += 64) {
        __syncthreads();
        // stage this half's K,V chunk (64x64 each = 8+8 segs over 4 waves)
#pragma unroll
        for (int i = 0; i < 2; i++) {
            int s = wsub * 2 + i;
            int row = s * 8 + lr0;
            int c = lc0 ^ (row & 7);
            gload16(k + (size_t)(b * 2048 + kc + row) * 1024 + hd * 64 + c * 8, Ksh + s * 512);
            gload16(vt + (size_t)(bh * 64 + row) * 2048 + kc + c * 8, Vsh + s * 512);
        }
        __syncthreads();

        // S^T: two 32k x 32q tiles, contraction over d=64 (4 x K=16)
        f32x16 accS[2];
#pragma unroll
        for (int mt = 0; mt < 2; mt++) {
#pragma unroll
            for (int r = 0; r < 16; r++) accS[mt][r] = 0.f;
#pragma unroll
            for (int dblk = 0; dblk < 4; dblk++) {
                bf16x8 aK = frag64(Ksh, mt * 32 + l31, dblk * 2 + h);
                accS[mt] = __builtin_amdgcn_mfma_f32_32x32x16_bf16(aK, qB[dblk], accS[mt], 0, 0, 0);
            }
        }

        // sigmoid + pack to bf16 pairs: group g regs 4g..4g+3 (k = 8g+4h..+3)
        u32 pg[2][4][2];
#pragma unroll
        for (int mt = 0; mt < 2; mt++)
#pragma unroll
            for (int g = 0; g < 4; g++) {
                float p[4];
#pragma unroll
                for (int e = 0; e < 4; e++) {
                    float t = __builtin_fmaf(accS[mt][g * 4 + e], NLOG2E, BIAS_L2E);
                    float u = __builtin_amdgcn_exp2f(t);
                    p[e] = __builtin_amdgcn_rcpf(1.0f + u);
                }
                pg[mt][g][0] = pk_hi(p[0], p[1]);
                pg[mt][g][1] = pk_hi(p[2], p[3]);
            }

        // PV: build A-frags via shfl_xor(32), accumulate O (2 d-tiles)
#pragma unroll
        for (int mt = 0; mt < 2; mt++)
#pragma unroll
            for (int kblk = 0; kblk < 2; kblk++) {
                int glo = kblk * 2, ghi = kblk * 2 + 1;
                u32 x0 = (u32)__shfl_xor((int)pg[mt][glo][0], 32, 64);
                u32 x1 = (u32)__shfl_xor((int)pg[mt][glo][1], 32, 64);
                u32 y0 = (u32)__shfl_xor((int)pg[mt][ghi][0], 32, 64);
                u32 y1 = (u32)__shfl_xor((int)pg[mt][ghi][1], 32, 64);
                u32x4 fr;
                fr[0] = h ? y0 : pg[mt][glo][0];
                fr[1] = h ? y1 : pg[mt][glo][1];
                fr[2] = h ? pg[mt][ghi][0] : x0;
                fr[3] = h ? pg[mt][ghi][1] : x1;
                bf16x8 aP = __builtin_bit_cast(bf16x8, fr);
#pragma unroll
                for (int dt = 0; dt < 2; dt++) {
                    bf16x8 bV = frag64(Vsh, dt * 32 + l31, mt * 4 + kblk * 2 + h);
                    accO[dt] = __builtin_amdgcn_mfma_f32_32x32x16_bf16(aP, bV, accO[dt], 0, 0, 0);
                }
            }
    }

    // merge k-halves through LDS; kh=0 waves write final ctx
    __syncthreads();
    if (kh == 1) {
#pragma unroll
        for (int dt = 0; dt < 2; dt++)
#pragma unroll
            for (int r = 0; r < 16; r++) {
                int ql = qsub * 32 + (r & 3) + 8 * (r >> 2) + 4 * h;
                Obuf[ql * 64 + dt * 32 + l31] = accO[dt][r];
            }
    }
    __syncthreads();
    if (kh == 0) {
#pragma unroll
        for (int dt = 0; dt < 2; dt++)
#pragma unroll
            for (int r = 0; r < 16; r++) {
                int ql = qsub * 32 + (r & 3) + 8 * (r >> 2) + 4 * h;
                float s = accO[dt][r] + Obuf[ql * 64 + dt * 32 + l31];
                ctx[(size_t)(b * 2048 + q0 + ql) * 1024 + hd * 64 + dt * 32 + l31] = f2bf(s);
            }
    }
}

// ---------------------------------------------------------------------------
// prep: fp32->bf16 of 4 weights (blocks 0..4095) + key_feats (4096..6143),
// then row-LN of query (blocks 6144..10239). One launch.
// ---------------------------------------------------------------------------
__global__ __launch_bounds__(256) void prep(const float* __restrict__ w0, const float* __restrict__ w1,
                                            const float* __restrict__ w2, const float* __restrict__ w3,
                                            const float* __restrict__ kf, const float* __restrict__ qf,
                                            const float* __restrict__ lnq_s, const float* __restrict__ lnq_b,
                                            u16* __restrict__ wdst, u16* __restrict__ kdst,
                                            u16* __restrict__ xq) {
    const int bx = blockIdx.x;
    const int tid = threadIdx.x;
    if (bx < 6144) {
        size_t e = ((size_t)bx * 256 + tid) * 4;
        const float* src;
        u16* dst;
        if (e < 4194304) {
            src = ((e >> 20) == 0 ? w0 : (e >> 20) == 1 ? w1 : (e >> 20) == 2 ? w2 : w3) + (e & 1048575);
            dst = wdst + e;
        } else {
            size_t off = e - 4194304;
            src = kf + off;
            dst = kdst + off;
        }
        float4 xv = *(const float4*)src;
        u16x4 o;
        o[0] = f2bf(xv.x);
        o[1] = f2bf(xv.y);
        o[2] = f2bf(xv.z);
        o[3] = f2bf(xv.w);
        *(u16x4*)dst = o;
    } else {
        __shared__ float s1buf[4], s2buf[4];
        const int row = bx - 6144;
        const size_t base = (size_t)row * 1024 + tid * 4;
        const float4 xv = *(const float4*)(qf + base);
        float s1 = xv.x + xv.y + xv.z + xv.w;
        float s2 = xv.x * xv.x + xv.y * xv.y + xv.z * xv.z + xv.w * xv.w;
        int lane = tid & 63, wave = tid >> 6;
#pragma unroll
        for (int off = 32; off > 0; off >>= 1) {
            s1 += __shfl_down(s1, off, 64);
            s2 += __shfl_down(s2, off, 64);
        }
        if (lane == 0) { s1buf[wave] = s1; s2buf[wave] = s2; }
        __syncthreads();
        s1 = s1buf[0] + s1buf[1] + s1buf[2] + s1buf[3];
        s2 = s2buf[0] + s2buf[1] + s2buf[2] + s2buf[3];
        float mu = s1 * (1.0f / 1024.0f);
        float var = s2 * (1.0f / 1024.0f) - mu * mu;
        float rs = rsqrtf(var + LN_EPS);
        const float4 scv = *(const float4*)(lnq_s + tid * 4);
        const float4 bsv = *(const float4*)(lnq_b + tid * 4);
        u16x4 o;
        o[0] = f2bf((xv.x - mu) * rs * scv.x + bsv.x);
        o[1] = f2bf((xv.y - mu) * rs * scv.y + bsv.y);
        o[2] = f2bf((xv.z - mu) * rs * scv.z + bsv.z);
        o[3] = f2bf((xv.w - mu) * rs * scv.w + bsv.w);
        *(u16x4*)(xq + base) = o;
    }
}

// ---------------------------------------------------------------------------
// Final: out = LN(resid + gamma*(o0+o1+o2+o3)) (fp32, bf16 partials)
// ---------------------------------------------------------------------------
__global__ __launch_bounds__(256) void final_ln(const float* __restrict__ resid,
                                                const u16* __restrict__ opre,
                                                const float* __restrict__ gamma,
                                                const float* __restrict__ sc,
                                                const float* __restrict__ bs,
                                                float* __restrict__ out) {
    __shared__ float s1buf[4], s2buf[4];
    const int row = blockIdx.x;
    const int tid = threadIdx.x;
    const size_t base = (size_t)row * 1024 + tid * 4;
    float4 rv = *(const float4*)(resid + base);
    u16x4 p0 = *(const u16x4*)(opre + base);
    u16x4 p1 = *(const u16x4*)(opre + 4194304 + base);
    u16x4 p2 = *(const u16x4*)(opre + 8388608 + base);
    u16x4 p3 = *(const u16x4*)(opre + 12582912 + base);
    float4 gv = *(const float4*)(gamma + tid * 4);
    float4 xv;
    xv.x = rv.x + gv.x * ((bf2f(p0[0]) + bf2f(p1[0])) + (bf2f(p2[0]) + bf2f(p3[0])));
    xv.y = rv.y + gv.y * ((bf2f(p0[1]) + bf2f(p1[1])) + (bf2f(p2[1]) + bf2f(p3[1])));
    xv.z = rv.z + gv.z * ((bf2f(p0[2]) + bf2f(p1[2])) + (bf2f(p2[2]) + bf2f(p3[2])));
    xv.w = rv.w + gv.w * ((bf2f(p0[3]) + bf2f(p1[3])) + (bf2f(p2[3]) + bf2f(p3[3])));
    float s1 = xv.x + xv.y + xv.z + xv.w;
    float s2 = xv.x * xv.x + xv.y * xv.y + xv.z * xv.z + xv.w * xv.w;
    int lane = tid & 63, wave = tid >> 6;
#pragma unroll
    for (int off = 32; off > 0; off >>= 1) {
        s1 += __shfl_down(s1, off, 64);
        s2 += __shfl_down(s2, off, 64);
    }
    if (lane == 0) { s1buf[wave] = s1; s2buf[wave] = s2; }
    __syncthreads();
    s1 = s1buf[0] + s1buf[1] + s1buf[2] + s1buf[3];
    s2 = s2buf[0] + s2buf[1] + s2buf[2] + s2buf[3];
    float mu = s1 * (1.0f / 1024.0f);
    float var = s2 * (1.0f / 1024.0f) - mu * mu;
    float rs = rsqrtf(var + LN_EPS);
    const float4 scv = *(const float4*)(sc + tid * 4);
    const float4 bsv = *(const float4*)(bs + tid * 4);
    float4 o;
    o.x = (xv.x - mu) * rs * scv.x + bsv.x;
    o.y = (xv.y - mu) * rs * scv.y + bsv.y;
    o.z = (xv.z - mu) * rs * scv.z + bsv.z;
    o.w = (xv.w - mu) * rs * scv.w + bsv.w;
    *(float4*)(out + base) = o;
}

extern "C" void kernel_launch(void* const* d_in, const int* in_sizes, int n_in,
                              void* d_out, int out_size, void* d_ws, size_t ws_size,
                              hipStream_t stream) {
    const float* qf    = (const float*)d_in[0];
    const float* kf    = (const float*)d_in[1];
    const float* Wq    = (const float*)d_in[2];
    const float* Wk    = (const float*)d_in[3];
    const float* Wv    = (const float*)d_in[4];
    const float* Wo    = (const float*)d_in[5];
    const float* qn_s  = (const float*)d_in[6];
    const float* qn_b  = (const float*)d_in[7];
    const float* kn_s  = (const float*)d_in[8];
    const float* kn_b  = (const float*)d_in[9];
    const float* lnq_s = (const float*)d_in[10];
    const float* lnq_b = (const float*)d_in[11];
    const float* lno_s = (const float*)d_in[12];
    const float* lno_b = (const float*)d_in[13];
    const float* gamma = (const float*)d_in[14];
    float* out = (float*)d_out;

    char* ws = (char*)d_ws;
    const size_t MB = 1024 * 1024;
    u16* Wqb   = (u16*)(ws + 0 * MB);   // 4 weights contiguous, 8 MB
    u16* Wkb   = (u16*)(ws + 2 * MB);
    u16* Wvb   = (u16*)(ws + 4 * MB);
    u16* Wob   = (u16*)(ws + 6 * MB);
    u16* xq    = (u16*)(ws + 8 * MB);    // dead after gemm_qkv
    u16* ctx   = (u16*)(ws + 8 * MB);    // reuse xq (attn writes merged ctx)
    u16* keyb  = (u16*)(ws + 16 * MB);   // dead after gemm_qkv
    u16* qln   = (u16*)(ws + 24 * MB);   // dead after attn
    u16* kln   = (u16*)(ws + 32 * MB);   // dead after attn
    u16* vt    = (u16*)(ws + 48 * MB);   // written by gemm_qkv z=2, dead after attn
    u16* opre  = (u16*)(ws + 24 * MB);   // 4 x 8 MB partials (reuse 24..56)

    prep<<<dim3(10240), 256, 0, stream>>>(Wq, Wk, Wv, Wo, kf, qf, lnq_s, lnq_b, Wqb, keyb, xq);

    gemm_qkv<<<dim3(32, 8, 3), 256, 0, stream>>>(xq, keyb, Wqb, Wkb, Wvb,
                                                 qn_s, qn_b, kn_s, kn_b, qln, kln, vt);

    attn_sigmoid_v7<<<dim3(16, 16, 2), 512, 0, stream>>>(qln, kln, vt, ctx);

    gemm_o<<<dim3(32, 8, 4), 256, 0, stream>>>(ctx, Wob, opre);
    final_ln<<<dim3(4096), 256, 0, stream>>>(qf, opre, gamma, lno_s, lno_b, out);
}